// Round 3
// baseline (777.895 us; speedup 1.0000x reference)
//
#include <hip/hip_runtime.h>
#include <hip/hip_bf16.h>
#include <math.h>

#define BB 8
#define NN 4096
#define KNN 20
#define CH 64
#define SAMPLES (BB*NN*KNN)   /* 655360 */
#define EPSF 1e-5f
#define SLOPE 0.2f
#define MCOPY 32              /* mstats copies to spread atomic contention */

typedef float f32x4 __attribute__((ext_vector_type(4)));
typedef short bf16x8 __attribute__((ext_vector_type(8)));

/* decode order-preserving uint back to float */
__device__ __forceinline__ float key_decode(unsigned e) {
    return __uint_as_float((e & 0x80000000u) ? (e ^ 0x80000000u) : ~e);
}

/* ---------------- K0: per-batch: build pts4 + bitonic sort by x + zero stats --- */
__global__ __launch_bounds__(1024) void sort_kernel(const float* __restrict__ x,
        float4* __restrict__ pts4, float4* __restrict__ sp4, int* __restrict__ sidx,
        int* __restrict__ rankArr, double* __restrict__ zreg) {
#pragma clang fp contract(off)
    __shared__ unsigned long long S[NN];                     /* 32 KB */
    const int tid = threadIdx.x;
    const int b = blockIdx.x;
    if (b == 0 && tid < 992) zreg[tid] = 0.0;     /* mstats(864d) + stats2f(128d) */
    const float* xb = x + (size_t)b * 3 * NN;
    for (int i = tid; i < NN; i += 1024) {
        float mx = xb[i], my = xb[NN + i], mz = xb[2*NN + i];
        float sq = mx*mx; sq += my*my; sq += mz*mz;          /* ref summation order */
        pts4[(b << 12) + i] = make_float4(-2.0f*mx, -2.0f*my, -2.0f*mz, sq);
        unsigned uu = __float_as_uint(mx);
        unsigned e = uu ^ (((unsigned)((int)uu >> 31)) | 0x80000000u);
        S[i] = ((unsigned long long)e << 32) | (unsigned)i;
    }
    __syncthreads();
    for (int k = 2; k <= NN; k <<= 1) {
        for (int j = k >> 1; j > 0; j >>= 1) {
#pragma unroll
            for (int tt = 0; tt < 2; ++tt) {
                int t = tid + tt*1024;            /* 2048 pairs */
                int i = ((t & ~(j - 1)) << 1) | (t & (j - 1));
                int h = i | j;
                unsigned long long a = S[i], c = S[h];
                bool up = ((i & k) == 0);
                if ((a > c) == up) { S[i] = c; S[h] = a; }
            }
            __syncthreads();
        }
    }
    for (int s = tid; s < NN; s += 1024) {
        int oi = (int)(unsigned)(S[s] & 0xFFFFFFFFu);
        float mx = xb[oi], my = xb[NN + oi], mz = xb[2*NN + oi];  /* recompute: no RAW */
        float sq = mx*mx; sq += my*my; sq += mz*mz;
        sp4[(b << 12) + s] = make_float4(-2.0f*mx, -2.0f*my, -2.0f*mz, sq);
        sidx[(b << 12) + s] = oi;
        rankArr[(b << 12) + oi] = s;
    }
}

/* ---------------- K1: exact KNN — transposed (1 lane = 1 query), 2-wave split.
   Wave 0: home-chunk prefill + right scan.  Wave 1: left scan (disjoint set).
   Candidates broadcast from prefetch registers via v_readlane (compile-time
   lane).  Top-20 lives in 40 VGPRs, updated by a branchless insert network
   gated by (push && key < k[19]) — direct insert, no LDS buffer, threshold
   tightens immediately.  Wave 1 posts its sorted 20 to LDS; wave 0 merges,
   writes idx_out, computes moments.  Selection semantics identical to the
   verified sweep: same fmaf filter + margin M, same exact-d ref-
   parenthesization, same (enc(d)<<32)|idx keys; per-wave prune uses the
   wave's own kthd (>= final kthd -> conservative, never skips a true NN). */

__device__ __forceinline__ float rlf(float v, int l) {
    return __uint_as_float((unsigned)__builtin_amdgcn_readlane((int)__float_as_uint(v), l));
}

/* branchless sorted insert of key into ascending k[0..19] (drops old k[19]) */
__device__ __forceinline__ void insert20(unsigned long long (&k)[20],
                                         const unsigned long long key) {
    bool c[20];
#pragma unroll
    for (int i = 0; i < 20; ++i) c[i] = key < k[i];
#pragma unroll
    for (int i = 19; i >= 1; --i)
        k[i] = c[i-1] ? k[i-1] : (c[i] ? key : k[i]);
    k[0] = c[0] ? key : k[0];
}

__device__ __forceinline__ void refresh(const unsigned long long k19,
        float& kthd, const float sqn, float& M, float& thr) {
#pragma clang fp contract(off)
    const unsigned e19 = (unsigned)(k19 >> 32);
    const float kd = key_decode(e19);
    kthd = (e19 != 0xFFFFFFFFu) ? kd : INFINITY;  /* guard: list not yet full */
    M = 1e-3f*(fabsf(kthd) + fabsf(sqn) + 1.0f);
    thr = (kthd - sqn) + M;
}

/* evaluate 16 candidates of register chunk C/Ci; DIR<0 walks t descending so
   left chunks are processed nearest-first (threshold tightens fastest). */
template<int T0, int DIR>
__device__ __forceinline__ void eval16(const float4 C, const int Ci,
        unsigned long long (&k)[20], const float qx, const float qy,
        const float qz, const float sqn, const float thr) {
#pragma clang fp contract(off)
#pragma unroll
    for (int u = 0; u < 16; ++u) {
        const int t = (DIR > 0) ? (T0 + u) : (T0 + 15 - u);
        const float px = rlf(C.x, t);
        const float py = rlf(C.y, t);
        const float pz = rlf(C.z, t);
        const float pw = rlf(C.w, t);
        const float sc = fmaf(px, qx, fmaf(py, qy, fmaf(pz, qz, pw)));
        const bool push = sc <= thr;
        if (__any(push)) {
            const int pidx = __builtin_amdgcn_readlane(Ci, t);
            const float mx = -0.5f*px, my = -0.5f*py, mz = -0.5f*pz;
            float inner = qx*mx; inner += qy*my; inner += qz*mz;
            const float d = (sqn - 2.0f*inner) + pw;    /* ref parenthesization */
            const unsigned uu = __float_as_uint(d);
            const unsigned e = uu ^ (((unsigned)((int)uu >> 31)) | 0x80000000u);
            const unsigned long long keyv =
                ((unsigned long long)e << 32) | (unsigned)pidx;
            const bool acc = push && (keyv < k[19]);
            if (__any(acc)) { if (acc) insert20(k, keyv); }
        }
    }
}

__global__ __launch_bounds__(128) void knn_kernel(const float4* __restrict__ pts4,
        const float4* __restrict__ sp4, const int* __restrict__ sidx,
        int* __restrict__ idx_out, double* __restrict__ mstats) {
#pragma clang fp contract(off)
    __shared__ unsigned long long MERGE[KNN*64];             /* 10 KB */

    const int tid  = threadIdx.x;
    const int lane = tid & 63;
    const int w    = tid >> 6;                    /* 0: home+right, 1: left */
    const int Q0 = blockIdx.x << 6;               /* global sorted rank base */
    const int b  = Q0 >> 12;
    const int r0 = Q0 & (NN - 1);                 /* multiple of 64 */
    const float4* sb = sp4 + ((size_t)b << 12);
    const int*    si = sidx + ((size_t)b << 12);

    /* lane's own query IS slot `lane` of the home chunk */
    const float4 R0 = sb[r0 + lane];
    const float qx = -0.5f*R0.x, qy = -0.5f*R0.y, qz = -0.5f*R0.z;
    const float sqn = R0.w;

    unsigned long long k[20];
#pragma unroll
    for (int j = 0; j < 20; ++j) k[j] = ~0ull;
    float kthd = INFINITY, M = INFINITY, thr = INFINITY;

    if (w == 0) {
        /* prefill on home chunk, threshold refreshed every 16 */
        const int Ri0 = si[r0 + lane];
        int hi = r0 + 64;
        bool dr = (hi == NN);
        float4 RR = R0; int RiR = 0;
        if (!dr) { RR = sb[hi + lane]; RiR = si[hi + lane]; }   /* prefetch */
        eval16<0,1> (R0, Ri0, k, qx,qy,qz,sqn, thr); refresh(k[19], kthd, sqn, M, thr);
        eval16<16,1>(R0, Ri0, k, qx,qy,qz,sqn, thr); refresh(k[19], kthd, sqn, M, thr);
        eval16<32,1>(R0, Ri0, k, qx,qy,qz,sqn, thr); refresh(k[19], kthd, sqn, M, thr);
        eval16<48,1>(R0, Ri0, k, qx,qy,qz,sqn, thr); refresh(k[19], kthd, sqn, M, thr);
        while (!dr) {
            const float xr = rlf(RR.x, 0);        /* nearest slot of chunk */
            const float dxr = (-0.5f*xr) - qx;
            if (__all(dxr*dxr > kthd + M)) break;
            const float4 C = RR; const int Ci = RiR;
            const int hi2 = hi + 64;
            if (hi2 < NN) { RR = sb[hi2 + lane]; RiR = si[hi2 + lane]; }
            eval16<0,1> (C, Ci, k, qx,qy,qz,sqn, thr); refresh(k[19], kthd, sqn, M, thr);
            eval16<16,1>(C, Ci, k, qx,qy,qz,sqn, thr); refresh(k[19], kthd, sqn, M, thr);
            eval16<32,1>(C, Ci, k, qx,qy,qz,sqn, thr); refresh(k[19], kthd, sqn, M, thr);
            eval16<48,1>(C, Ci, k, qx,qy,qz,sqn, thr); refresh(k[19], kthd, sqn, M, thr);
            hi = hi2; dr = (hi == NN);
        }
    } else {
        int lo = r0;
        bool dl = (lo == 0);
        float4 RL = R0; int RiL = 0;
        if (!dl) { RL = sb[lo - 64 + lane]; RiL = si[lo - 64 + lane]; }
        while (!dl) {
            /* nearest slot of left chunk = 63; thr=INF 1st pass never prunes */
            const float xl = rlf(RL.x, 63);
            const float dxl = qx - (-0.5f*xl);
            if (__all(dxl*dxl > kthd + M)) break;
            const float4 C = RL; const int Ci = RiL;
            const int lo2 = lo - 64;
            if (lo2 > 0) { RL = sb[lo2 - 64 + lane]; RiL = si[lo2 - 64 + lane]; }
            eval16<48,-1>(C, Ci, k, qx,qy,qz,sqn, thr); refresh(k[19], kthd, sqn, M, thr);
            eval16<32,-1>(C, Ci, k, qx,qy,qz,sqn, thr); refresh(k[19], kthd, sqn, M, thr);
            eval16<16,-1>(C, Ci, k, qx,qy,qz,sqn, thr); refresh(k[19], kthd, sqn, M, thr);
            eval16<0,-1> (C, Ci, k, qx,qy,qz,sqn, thr); refresh(k[19], kthd, sqn, M, thr);
            lo = lo2; dl = (lo == 0);
        }
#pragma unroll
        for (int j = 0; j < KNN; ++j) MERGE[(j << 6) + lane] = k[j];
    }
    __syncthreads();
    if (w == 1) return;

    /* merge wave1's sorted 20 (disjoint candidate set: no duplicate keys) */
    {
        unsigned long long mk[KNN];
#pragma unroll
        for (int j = 0; j < KNN; ++j) mk[j] = MERGE[(j << 6) + lane];
#pragma unroll
        for (int j = 0; j < KNN; ++j) {
            const unsigned long long key = mk[j];
            const bool acc = key < k[19];
            if (__any(acc)) { if (acc) insert20(k, key); }
        }
    }

    /* transpose top-20 through LDS (reuse MERGE) for coalesced idx_out writes */
    unsigned* TB = (unsigned*)MERGE;
    __builtin_amdgcn_wave_barrier();
#pragma unroll
    for (int j = 0; j < KNN; ++j)
        TB[lane*21 + j] = (unsigned)(k[j] & 0xFFFFFFFFull);
    __builtin_amdgcn_wave_barrier();
    int* iout = idx_out + (size_t)Q0 * KNN;
#pragma unroll
    for (int u = 0; u < KNN; ++u) {
        int g = (u << 6) + lane;                  /* 1280 contiguous ints */
        iout[g] = (int)TB[(g / KNN)*21 + (g % KNN)];
    }

    /* moments epilogue: each lane sums over its own 20 neighbors */
    const float4* pb = pts4 + ((size_t)b << 12);
    float nx=0.f, ny=0.f, nz=0.f, xx=0.f, xy=0.f, xz=0.f, yy=0.f, yz=0.f, zz=0.f;
#pragma unroll
    for (int j = 0; j < KNN; ++j) {
        int nb = (int)(unsigned)(k[j] & 0xFFFFFFFFull);
        float4 pn = pb[nb];
        float ax = -0.5f*pn.x, ay = -0.5f*pn.y, az = -0.5f*pn.z;
        nx += ax; ny += ay; nz += az;
        xx += ax*ax; xy += ax*ay; xz += ax*az;
        yy += ay*ay; yz += ay*az; zz += az*az;
    }
    double* msd = &mstats[(blockIdx.x & (MCOPY-1))*27];
#define RED27(v, i) { float r_ = (v); \
    r_ += __shfl_xor(r_, 1);  r_ += __shfl_xor(r_, 2);  r_ += __shfl_xor(r_, 4); \
    r_ += __shfl_xor(r_, 8);  r_ += __shfl_xor(r_, 16); r_ += __shfl_xor(r_, 32); \
    if (lane == 0) atomicAdd(&msd[i], (double)r_); }
    RED27(nx, 0) RED27(ny, 1) RED27(nz, 2)
    RED27(qx, 3) RED27(qy, 4) RED27(qz, 5)
    RED27(xx, 6) RED27(xy, 7) RED27(xz, 8)
    RED27(yy, 9) RED27(yz, 10) RED27(zz, 11)
    RED27(nx*qx, 12) RED27(nx*qy, 13) RED27(nx*qz, 14)
    RED27(ny*qx, 15) RED27(ny*qy, 16) RED27(ny*qz, 17)
    RED27(nz*qx, 18) RED27(nz*qy, 19) RED27(nz*qz, 20)
    RED27(qx*qx, 21) RED27(qx*qy, 22) RED27(qx*qz, 23)
    RED27(qy*qy, 24) RED27(qy*qz, 25) RED27(qz*qz, 26)
#undef RED27
}

/* split fp32 -> bf16 hi (truncate) + bf16 lo (truncated remainder) */
__device__ __forceinline__ void bsplit(float g, short& hi, short& lo) {
    unsigned bits = __float_as_uint(g);
    unsigned hbits = bits & 0xFFFF0000u;
    float rem = g - __uint_as_float(hbits);
    hi = (short)(bits >> 16);
    lo = (short)(__float_as_uint(rem) >> 16);
}

/* ---------------- K5: main pass — shared-leftover-tile split-bf16 MFMA --------- */
__global__ __launch_bounds__(256) void main_kernel(const int* __restrict__ idxb,
        const int* __restrict__ rankArr, const float4* __restrict__ pts4,
        const double* __restrict__ ms, const float* __restrict__ W1,
        const float* __restrict__ gamma1, const float* __restrict__ beta1,
        const float* __restrict__ W2,
        float* __restrict__ maxbuf, float* __restrict__ stats2f) {
    __shared__ __align__(16) short Thi[4][32*72];
    __shared__ __align__(16) short Tlo[4][32*72];
    __shared__ float chs[128];
    __shared__ float ab1s[128];
    __shared__ double msd[27];
    const int tid = threadIdx.x;
    const int lane = tid & 63;
    const int wv = __builtin_amdgcn_readfirstlane(tid >> 6);
    const int l15 = lane & 15;
    const int quad = lane >> 4;
    if (tid < 128) chs[tid] = 0.f;
    if (tid < 27) {                                /* sum the 32 mstats copies */
        double t = 0.0;
        for (int c = 0; c < MCOPY; ++c) t += ms[c*27 + tid];
        msd[tid] = t;
    }
    __syncthreads();
    if (tid < 64) {                                /* inline fin1m (bn1 affine) */
        int c = tid;
        double wu[3], wvv[3];
#pragma unroll
        for (int i = 0; i < 3; ++i) {
            wu[i] = (double)W1[c*6 + i];
            wvv[i] = (double)W1[c*6 + 3 + i] - wu[i];
        }
        const double S = (double)SAMPLES;
        double mean = (wu[0]*msd[0] + wu[1]*msd[1] + wu[2]*msd[2]
                     + 20.0*(wvv[0]*msd[3] + wvv[1]*msd[4] + wvv[2]*msd[5])) / S;
        double qM1 = wu[0]*wu[0]*msd[6] + wu[1]*wu[1]*msd[9] + wu[2]*wu[2]*msd[11]
                   + 2.0*(wu[0]*wu[1]*msd[7] + wu[0]*wu[2]*msd[8] + wu[1]*wu[2]*msd[10]);
        double cross = 0.0;
#pragma unroll
        for (int i = 0; i < 3; ++i)
#pragma unroll
            for (int j = 0; j < 3; ++j)
                cross += wu[i] * msd[12 + i*3 + j] * wvv[j];
        double qpp = wvv[0]*wvv[0]*msd[21] + wvv[1]*wvv[1]*msd[24] + wvv[2]*wvv[2]*msd[26]
                   + 2.0*(wvv[0]*wvv[1]*msd[22] + wvv[0]*wvv[2]*msd[23] + wvv[1]*wvv[2]*msd[25]);
        double e2 = (qM1 + 2.0*cross + 20.0*qpp) / S;
        double var = e2 - mean*mean;
        float a = (float)((double)gamma1[c] / sqrt(var + (double)EPSF));
        ab1s[c] = a;
        ab1s[64 + c] = beta1[c] - a * (float)mean;
    }
    __syncthreads();

    bf16x8 whi[8], wlo[8];
#pragma unroll
    for (int t = 0; t < 4; ++t)
#pragma unroll
    for (int f = 0; f < 2; ++f) {
        const int o = 16*t + l15;
        const int c0 = 32*f + quad*8;
        const float4* wr = (const float4*)(W2 + o*64 + c0);
        float4 w0 = wr[0], w1 = wr[1];
        float vals[8] = {w0.x,w0.y,w0.z,w0.w,w1.x,w1.y,w1.z,w1.w};
        bf16x8 h, l;
#pragma unroll
        for (int j = 0; j < 8; ++j) { short hj, lj; bsplit(vals[j], hj, lj); h[j]=hj; l[j]=lj; }
        whi[t*2+f] = h; wlo[t*2+f] = l;
    }

    const float w10 = W1[lane*6+0], w11 = W1[lane*6+1], w12 = W1[lane*6+2];
    const float w13 = W1[lane*6+3], w14 = W1[lane*6+4], w15 = W1[lane*6+5];
    const float a1 = ab1s[lane], b1 = ab1s[64 + lane];
    float ssum[4] = {0.f,0.f,0.f,0.f}, ssq[4] = {0.f,0.f,0.f,0.f};
    float lm[4][4];                                /* deferred tile1 max [point][t] */
    short* thi = &Thi[wv][0];
    short* tlo = &Tlo[wv][0];

    const int pt0 = (blockIdx.x * 4 + wv) * 4;
    const int b = pt0 >> 12;
    const float4* pb = pts4 + ((size_t)b << 12);
    const int* rnk = rankArr + ((size_t)b << 12);

    for (int p = 0; p < 4; ++p) {
        const int pt = pt0 + p;
        const float4 pc = pb[pt & (NN - 1)];
        const float X = -0.5f*pc.x, Y = -0.5f*pc.y, Z = -0.5f*pc.z;
        const float vc = (w13 - w10)*X + (w14 - w11)*Y + (w15 - w12)*Z;
        const int srow = rnk[pt & (NN - 1)];       /* uniform scalar lookup */
        const int* irow = idxb + ((size_t)((b << 12) + srow)) * KNN;
#pragma unroll
        for (int k = 0; k < KNN; ++k) {
            float4 pn = pb[irow[k]];
            float nx = -0.5f*pn.x, ny = -0.5f*pn.y, nz = -0.5f*pn.z;
            float uc = w10*nx + w11*ny + w12*nz;
            float g = a1 * (uc + vc) + b1;
            g = fmaxf(g, SLOPE * g);
            short hj, lj; bsplit(g, hj, lj);
            const int row = (k < 16) ? k : (16 + p*4 + (k - 16));
            thi[row*72 + lane] = hj;
            tlo[row*72 + lane] = lj;
        }
        __builtin_amdgcn_wave_barrier();

        bf16x8 ah1[2], al1[2];
#pragma unroll
        for (int f = 0; f < 2; ++f) {
            const int co = 32*f + quad*8;
            ah1[f] = *(const bf16x8*)&thi[l15*72 + co];
            al1[f] = *(const bf16x8*)&tlo[l15*72 + co];
        }

        f32x4 acc1[4];
#pragma unroll
        for (int t = 0; t < 4; ++t) acc1[t] = (f32x4)0.f;
#pragma unroll
        for (int t = 0; t < 4; ++t) {
#pragma unroll
            for (int f = 0; f < 2; ++f) {
                acc1[t] = __builtin_amdgcn_mfma_f32_16x16x32_bf16(ah1[f], whi[t*2+f], acc1[t], 0,0,0);
                acc1[t] = __builtin_amdgcn_mfma_f32_16x16x32_bf16(al1[f], whi[t*2+f], acc1[t], 0,0,0);
                acc1[t] = __builtin_amdgcn_mfma_f32_16x16x32_bf16(ah1[f], wlo[t*2+f], acc1[t], 0,0,0);
            }
        }
        __builtin_amdgcn_wave_barrier();           /* tile1 reads done before next p */

        /* tile1 epilogue: reduce over rows k=0..15 (quads), defer the write */
#pragma unroll
        for (int t = 0; t < 4; ++t) {
            float m1 = fmaxf(fmaxf(acc1[t][0], acc1[t][1]), fmaxf(acc1[t][2], acc1[t][3]));
            float s1 = acc1[t][0] + acc1[t][1] + acc1[t][2] + acc1[t][3];
            float q1 = acc1[t][0]*acc1[t][0] + acc1[t][1]*acc1[t][1]
                     + acc1[t][2]*acc1[t][2] + acc1[t][3]*acc1[t][3];
            m1 = fmaxf(m1, __shfl_xor(m1, 16)); m1 = fmaxf(m1, __shfl_xor(m1, 32));
            s1 += __shfl_xor(s1, 16); s1 += __shfl_xor(s1, 32);
            q1 += __shfl_xor(q1, 16); q1 += __shfl_xor(q1, 32);
            lm[p][t] = m1;
            ssum[t] += s1; ssq[t] += q1;
        }
    }

    /* combined leftover tile: rows = p*4+(k-16), read once, 24 MFMA */
    {
        bf16x8 ah2[2], al2[2];
#pragma unroll
        for (int f = 0; f < 2; ++f) {
            const int co = 32*f + quad*8;
            ah2[f] = *(const bf16x8*)&thi[(16 + l15)*72 + co];
            al2[f] = *(const bf16x8*)&tlo[(16 + l15)*72 + co];
        }
        f32x4 accC[4];
#pragma unroll
        for (int t = 0; t < 4; ++t) accC[t] = (f32x4)0.f;
#pragma unroll
        for (int t = 0; t < 4; ++t) {
#pragma unroll
            for (int f = 0; f < 2; ++f) {
                accC[t] = __builtin_amdgcn_mfma_f32_16x16x32_bf16(ah2[f], whi[t*2+f], accC[t], 0,0,0);
                accC[t] = __builtin_amdgcn_mfma_f32_16x16x32_bf16(al2[f], whi[t*2+f], accC[t], 0,0,0);
                accC[t] = __builtin_amdgcn_mfma_f32_16x16x32_bf16(ah2[f], wlo[t*2+f], accC[t], 0,0,0);
            }
        }
        /* C row = quad*4+reg -> point = quad, k = 16+reg. */
#pragma unroll
        for (int t = 0; t < 4; ++t) {
            float cm = fmaxf(fmaxf(accC[t][0], accC[t][1]), fmaxf(accC[t][2], accC[t][3]));
            float cs = accC[t][0] + accC[t][1] + accC[t][2] + accC[t][3];
            float cq = accC[t][0]*accC[t][0] + accC[t][1]*accC[t][1]
                     + accC[t][2]*accC[t][2] + accC[t][3]*accC[t][3];
            float lmq = (quad == 0) ? lm[0][t] : (quad == 1) ? lm[1][t]
                      : (quad == 2) ? lm[2][t] : lm[3][t];
            maxbuf[((size_t)(pt0 + quad) << 6) + 16*t + l15] = fmaxf(lmq, cm);
            cs += __shfl_xor(cs, 16); cs += __shfl_xor(cs, 32);
            cq += __shfl_xor(cq, 16); cq += __shfl_xor(cq, 32);
            ssum[t] += cs; ssq[t] += cq;
        }
    }

    if (quad == 0) {
#pragma unroll
        for (int t = 0; t < 4; ++t) {
            atomicAdd(&chs[16*t + l15], ssum[t]);
            atomicAdd(&chs[64 + 16*t + l15], ssq[t]);
        }
    }
    __syncthreads();
    if (tid < 128)
        atomicAdd(&stats2f[(blockIdx.x & 1)*128 + tid], chs[tid]);
}

/* ---------------- K7: epilogue — fin2 inlined; transpose + bn2 + lrelu --------- */
__global__ __launch_bounds__(256) void out_kernel(const float* __restrict__ maxbuf,
        const float* __restrict__ s2f, const float* __restrict__ gamma2,
        const float* __restrict__ beta2, float* __restrict__ out) {
    __shared__ float t[64][65];
    __shared__ float ab2s[128];
    const int tid = threadIdx.x;
    if (tid < 64) {                                /* inline fin2 */
        int o = tid;
        double sum = (double)s2f[o] + (double)s2f[128 + o];
        double sq  = (double)s2f[64 + o] + (double)s2f[192 + o];
        double cnt = (double)SAMPLES;
        double mean = sum / cnt;
        double var  = sq / cnt - mean*mean;
        float a = (float)((double)gamma2[o] / sqrt(var + (double)EPSF));
        ab2s[o] = a;
        ab2s[64 + o] = beta2[o] - a * (float)mean;
    }
    const int b = blockIdx.x >> 6;
    const int n0 = (blockIdx.x & 63) << 6;
#pragma unroll
    for (int i = 0; i < 16; ++i) {
        int r = (tid >> 6) + i*4;
        int c = tid & 63;
        t[r][c] = maxbuf[(((size_t)((b << 12) + n0 + r)) << 6) + c];
    }
    __syncthreads();
#pragma unroll
    for (int i = 0; i < 16; ++i) {
        int o = (tid >> 6) + i*4;
        int nn = tid & 63;
        float a = ab2s[o], bb = ab2s[64 + o];
        float h = a * t[nn][o] + bb;
        out[(((size_t)(b*64 + o)) << 12) + n0 + nn] = h >= 0.f ? h : SLOPE*h;
    }
}

extern "C" void kernel_launch(void* const* d_in, const int* in_sizes, int n_in,
                              void* d_out, int out_size, void* d_ws, size_t ws_size,
                              hipStream_t stream) {
    const float* x      = (const float*)d_in[0];
    const float* W1     = (const float*)d_in[1];
    const float* gamma1 = (const float*)d_in[2];
    const float* beta1  = (const float*)d_in[3];
    const float* W2     = (const float*)d_in[4];
    const float* gamma2 = (const float*)d_in[5];
    const float* beta2  = (const float*)d_in[6];
    float* out = (float*)d_out;

    char* ws = (char*)d_ws;
    int*    idxb    = (int*)   (ws + 0);           /* 2,621,440 B (sorted order) */
    float4* pts4    = (float4*)(ws + 2621440);     /* 512 KB */
    float4* sp4     = (float4*)(ws + 3145728);     /* 512 KB sorted pts */
    int*    sidx    = (int*)   (ws + 3670016);     /* 128 KB sorted->orig */
    int*    rankArr = (int*)   (ws + 3801088);     /* 128 KB orig->sorted */
    float*  maxbuf  = (float*) (ws + 19398656);    /* 8,388,608 B, (b,n,o) */
    double* mstats  = (double*)(ws + 27787264);    /* 32x27 doubles = 6912 B */
    float*  stats2f = (float*) (ws + 27794176);    /* 2x128 floats = 1024 B */
    double* zreg    = (double*)(ws + 27787264);    /* zero region: 992 doubles */

    sort_kernel <<<8, 1024, 0, stream>>>(x, pts4, sp4, sidx, rankArr, zreg);
    knn_kernel  <<<512, 128, 0, stream>>>(pts4, sp4, sidx, idxb, mstats);
    main_kernel <<<2048, 256, 0, stream>>>(idxb, rankArr, pts4, mstats, W1, gamma1,
                                           beta1, W2, maxbuf, stats2f);
    out_kernel  <<<512, 256, 0, stream>>>(maxbuf, stats2f, gamma2, beta2, out);
}

// Round 5
// 405.786 us; speedup vs baseline: 1.9170x; 1.9170x over previous
//
#include <hip/hip_runtime.h>
#include <hip/hip_bf16.h>
#include <math.h>

#define BB 8
#define NN 4096
#define KNN 20
#define CH 64
#define SAMPLES (BB*NN*KNN)   /* 655360 */
#define EPSF 1e-5f
#define SLOPE 0.2f
#define MCOPY 32              /* mstats copies to spread atomic contention */
#define WBCAP 24              /* per-wave per-lane buffer entries (guard at >=8, +16/eval16) */

typedef float f32x4 __attribute__((ext_vector_type(4)));
typedef short bf16x8 __attribute__((ext_vector_type(8)));
typedef unsigned long long ull;

/* decode order-preserving uint back to float */
__device__ __forceinline__ float key_decode(unsigned e) {
    return __uint_as_float((e & 0x80000000u) ? (e ^ 0x80000000u) : ~e);
}

/* ---------------- K0: per-batch: build pts4 + bitonic sort by x + zero stats --- */
__global__ __launch_bounds__(1024) void sort_kernel(const float* __restrict__ x,
        float4* __restrict__ pts4, float4* __restrict__ sp4, int* __restrict__ sidx,
        int* __restrict__ rankArr, double* __restrict__ zreg) {
#pragma clang fp contract(off)
    __shared__ unsigned long long S[NN];                     /* 32 KB */
    const int tid = threadIdx.x;
    const int b = blockIdx.x;
    if (b == 0 && tid < 992) zreg[tid] = 0.0;     /* mstats(864d) + stats2f(128d) */
    const float* xb = x + (size_t)b * 3 * NN;
    for (int i = tid; i < NN; i += 1024) {
        float mx = xb[i], my = xb[NN + i], mz = xb[2*NN + i];
        float sq = mx*mx; sq += my*my; sq += mz*mz;          /* ref summation order */
        pts4[(b << 12) + i] = make_float4(-2.0f*mx, -2.0f*my, -2.0f*mz, sq);
        unsigned uu = __float_as_uint(mx);
        unsigned e = uu ^ (((unsigned)((int)uu >> 31)) | 0x80000000u);
        S[i] = ((unsigned long long)e << 32) | (unsigned)i;
    }
    __syncthreads();
    for (int k = 2; k <= NN; k <<= 1) {
        for (int j = k >> 1; j > 0; j >>= 1) {
#pragma unroll
            for (int tt = 0; tt < 2; ++tt) {
                int t = tid + tt*1024;            /* 2048 pairs */
                int i = ((t & ~(j - 1)) << 1) | (t & (j - 1));
                int h = i | j;
                unsigned long long a = S[i], c = S[h];
                bool up = ((i & k) == 0);
                if ((a > c) == up) { S[i] = c; S[h] = a; }
            }
            __syncthreads();
        }
    }
    for (int s = tid; s < NN; s += 1024) {
        int oi = (int)(unsigned)(S[s] & 0xFFFFFFFFu);
        float mx = xb[oi], my = xb[NN + oi], mz = xb[2*NN + oi];  /* recompute: no RAW */
        float sq = mx*mx; sq += my*my; sq += mz*mz;
        sp4[(b << 12) + s] = make_float4(-2.0f*mx, -2.0f*my, -2.0f*mz, sq);
        sidx[(b << 12) + s] = oi;
        rankArr[(b << 12) + oi] = s;
    }
}

/* ---------------- K1: exact KNN — transposed (1 lane = 1 query), 4-wave split.
   One 256-thread block per 64 consecutive sorted ranks.  Chunk ownership
   (disjoint, monotone-in-x arithmetic sequences; r0 = group base):
     wave0: r0, r0+128, ...   wave1: r0+64, r0+192, ...
     wave2: r0-64, r0-192,... wave3: r0-128, r0-256, ...
   Candidates broadcast from prefetch registers via v_readlane (compile-time
   lane).  Survivors append to a per-lane per-wave LDS buffer ([entry][lane],
   512B entry stride: 2 lanes/bank = conflict-free); BATCHED flush merges into
   a sorted 40-VGPR top-20 via a branchless insert network (insert20 inlined
   only in flush/merge: keeps k[] register-resident).  Each wave prunes with
   its own kthd (>= true kthd -> conservative, never skips a true neighbor).
   Waves 1-3 post sorted lists to their idle BUF areas; wave 0 merges with
   early-out, writes idx_out, computes moments.  Selection semantics identical
   to the verified sweep: same fmaf filter + margin M, same exact-d ref-
   parenthesization, same (enc(d)<<32)|idx keys. */

__device__ __forceinline__ float rlf(float v, int l) {
    return __uint_as_float((unsigned)__builtin_amdgcn_readlane((int)__float_as_uint(v), l));
}

/* branchless sorted insert of key into ascending k[0..19] (drops old k[19]) */
__device__ __forceinline__ void insert20(ull (&k)[20], const ull key) {
    bool c[20];
#pragma unroll
    for (int i = 0; i < 20; ++i) c[i] = key < k[i];
#pragma unroll
    for (int i = 19; i >= 1; --i)
        k[i] = c[i-1] ? k[i-1] : (c[i] ? key : k[i]);
    k[0] = c[0] ? key : k[0];
}

__device__ __forceinline__ void refresh(const ull k19,
        float& kthd, const float sqn, float& M, float& thr) {
#pragma clang fp contract(off)
    const unsigned e19 = (unsigned)(k19 >> 32);
    const float kd = key_decode(e19);
    kthd = (e19 != 0xFFFFFFFFu) ? kd : INFINITY;  /* guard: list not yet full */
    M = 1e-3f*(fabsf(kthd) + fabsf(sqn) + 1.0f);
    thr = (kthd - sqn) + M;
}

__device__ __forceinline__ void flush20(ull* buf, const int lane, int& cnt,
        ull (&k)[20], float& kthd, const float sqn, float& M, float& thr) {
#pragma clang fp contract(off)
    ull key = buf[lane];                          /* j=0 prefetched */
    int j = 0;
    while (__any(j < cnt)) {
        ull keyn = buf[((j + 1) << 6) + lane];    /* hide LDS latency */
        const bool acc = (j < cnt) && (key < k[19]);
        if (__any(acc)) { if (acc) insert20(k, key); }
        key = keyn; ++j;
    }
    cnt = 0;
    refresh(k[19], kthd, sqn, M, thr);
}

/* evaluate 16 candidates of register chunk C/Ci; DIR<0 walks t descending so
   left chunks are processed nearest-first (threshold tightens fastest). */
template<int T0, int DIR>
__device__ __forceinline__ void eval16(const float4 C, const int Ci, ull* buf,
        const int lane, const float qx, const float qy, const float qz,
        const float sqn, const float thr, int& cnt) {
#pragma clang fp contract(off)
#pragma unroll
    for (int u = 0; u < 16; ++u) {
        const int t = (DIR > 0) ? (T0 + u) : (T0 + 15 - u);
        const float px = rlf(C.x, t);
        const float py = rlf(C.y, t);
        const float pz = rlf(C.z, t);
        const float pw = rlf(C.w, t);
        const float sc = fmaf(px, qx, fmaf(py, qy, fmaf(pz, qz, pw)));
        const bool push = sc <= thr;
        if (__any(push)) {
            const int pidx = __builtin_amdgcn_readlane(Ci, t);
            const float mx = -0.5f*px, my = -0.5f*py, mz = -0.5f*pz;
            float inner = qx*mx; inner += qy*my; inner += qz*mz;
            const float d = (sqn - 2.0f*inner) + pw;    /* ref parenthesization */
            const unsigned uu = __float_as_uint(d);
            const unsigned e = uu ^ (((unsigned)((int)uu >> 31)) | 0x80000000u);
            const ull keyv = ((ull)e << 32) | (unsigned)pidx;
            if (push) { buf[(cnt << 6) + lane] = keyv; ++cnt; }
        }
    }
}

/* scan the arithmetic chunk sequence s, s+DIR*128, ... within [0, NN-64] */
template<int DIR>
__device__ __forceinline__ void scan(const float4* __restrict__ sb,
        const int* __restrict__ si, int s, ull (&k)[20], ull* buf,
        const int lane, const float qx, const float qy, const float qz,
        const float sqn, float& kthd, float& M, float& thr, int& cnt) {
#pragma clang fp contract(off)
    if (s < 0 || s > NN - 64) return;
    float4 C = sb[s + lane];
    int Ci = si[s + lane];
    while (true) {
        /* prune vs nearest slot of current chunk (thr=INF never prunes) */
        const float xn = rlf(C.x, (DIR > 0) ? 0 : 63);
        const float dx = (DIR > 0) ? ((-0.5f*xn) - qx) : (qx - (-0.5f*xn));
        if (__all(dx*dx > kthd + M)) break;
        const int s2 = s + DIR*128;
        const bool more = (s2 >= 0) && (s2 <= NN - 64);
        float4 Cn; int Cin = 0;
        if (more) { Cn = sb[s2 + lane]; Cin = si[s2 + lane]; }  /* prefetch */
        if (DIR > 0) {
            eval16<0,1> (C, Ci, buf, lane, qx,qy,qz,sqn, thr, cnt);
            if (__any(cnt >= 8)) flush20(buf, lane, cnt, k, kthd, sqn, M, thr);
            eval16<16,1>(C, Ci, buf, lane, qx,qy,qz,sqn, thr, cnt);
            if (__any(cnt >= 8)) flush20(buf, lane, cnt, k, kthd, sqn, M, thr);
            eval16<32,1>(C, Ci, buf, lane, qx,qy,qz,sqn, thr, cnt);
            if (__any(cnt >= 8)) flush20(buf, lane, cnt, k, kthd, sqn, M, thr);
            eval16<48,1>(C, Ci, buf, lane, qx,qy,qz,sqn, thr, cnt);
        } else {
            eval16<48,-1>(C, Ci, buf, lane, qx,qy,qz,sqn, thr, cnt);
            if (__any(cnt >= 8)) flush20(buf, lane, cnt, k, kthd, sqn, M, thr);
            eval16<32,-1>(C, Ci, buf, lane, qx,qy,qz,sqn, thr, cnt);
            if (__any(cnt >= 8)) flush20(buf, lane, cnt, k, kthd, sqn, M, thr);
            eval16<16,-1>(C, Ci, buf, lane, qx,qy,qz,sqn, thr, cnt);
            if (__any(cnt >= 8)) flush20(buf, lane, cnt, k, kthd, sqn, M, thr);
            eval16<0,-1> (C, Ci, buf, lane, qx,qy,qz,sqn, thr, cnt);
        }
        flush20(buf, lane, cnt, k, kthd, sqn, M, thr);   /* refresh for prune */
        if (!more) break;
        C = Cn; Ci = Cin; s = s2;
    }
}

__global__ __launch_bounds__(256) void knn_kernel(const float4* __restrict__ pts4,
        const float4* __restrict__ sp4, const int* __restrict__ sidx,
        int* __restrict__ idx_out, double* __restrict__ mstats) {
#pragma clang fp contract(off)
    __shared__ ull BUF[4][WBCAP*64];              /* 48 KB */

    const int tid  = threadIdx.x;
    const int lane = tid & 63;
    const int w    = tid >> 6;
    const int Q0 = blockIdx.x << 6;               /* global sorted rank base */
    const int b  = Q0 >> 12;
    const int r0 = Q0 & (NN - 1);                 /* multiple of 64 */
    const float4* sb = sp4 + ((size_t)b << 12);
    const int*    si = sidx + ((size_t)b << 12);

    /* lane's own query IS slot `lane` of the home chunk */
    const float4 R0 = sb[r0 + lane];
    const float qx = -0.5f*R0.x, qy = -0.5f*R0.y, qz = -0.5f*R0.z;
    const float sqn = R0.w;

    ull k[20];
#pragma unroll
    for (int j = 0; j < 20; ++j) k[j] = ~0ull;
    float kthd = INFINITY, M = INFINITY, thr = INFINITY;
    int cnt = 0;
    ull* buf = &BUF[w][0];

    /* disjoint chunk sequences; each wave's first chunk cold-starts with
       thr=INF (all pushed, guard flushes every 16 -> threshold tightens) */
    if      (w == 0) scan< 1>(sb, si, r0,       k, buf, lane, qx,qy,qz,sqn, kthd, M, thr, cnt);
    else if (w == 1) scan< 1>(sb, si, r0 + 64,  k, buf, lane, qx,qy,qz,sqn, kthd, M, thr, cnt);
    else if (w == 2) scan<-1>(sb, si, r0 - 64,  k, buf, lane, qx,qy,qz,sqn, kthd, M, thr, cnt);
    else             scan<-1>(sb, si, r0 - 128, k, buf, lane, qx,qy,qz,sqn, kthd, M, thr, cnt);

    if (w != 0) {                                 /* post sorted list */
#pragma unroll
        for (int j = 0; j < KNN; ++j) buf[(j << 6) + lane] = k[j];
    }
    __syncthreads();
    if (w != 0) return;

    /* merge waves 1..3 (disjoint candidate sets: no duplicate keys).
       Sorted sources -> early-out when all lanes reject. */
#pragma unroll 1
    for (int w2 = 1; w2 < 4; ++w2) {
        ull* src = &BUF[w2][0];
#pragma unroll 1
        for (int j = 0; j < KNN; ++j) {
            const ull key = src[(j << 6) + lane];
            const bool acc = key < k[19];
            if (__all(!acc)) break;
            if (acc) insert20(k, key);
        }
    }

    /* transpose top-20 through LDS (reuse wave0 BUF) for coalesced writes */
    unsigned* TB = (unsigned*)&BUF[0][0];
    __builtin_amdgcn_wave_barrier();
#pragma unroll
    for (int j = 0; j < KNN; ++j)
        TB[lane*21 + j] = (unsigned)(k[j] & 0xFFFFFFFFull);
    __builtin_amdgcn_wave_barrier();
    int* iout = idx_out + (size_t)Q0 * KNN;
#pragma unroll
    for (int u = 0; u < KNN; ++u) {
        int g = (u << 6) + lane;                  /* 1280 contiguous ints */
        iout[g] = (int)TB[(g / KNN)*21 + (g % KNN)];
    }

    /* moments epilogue: each lane sums over its own 20 neighbors */
    const float4* pb = pts4 + ((size_t)b << 12);
    float nx=0.f, ny=0.f, nz=0.f, xx=0.f, xy=0.f, xz=0.f, yy=0.f, yz=0.f, zz=0.f;
#pragma unroll
    for (int j = 0; j < KNN; ++j) {
        int nb = (int)(unsigned)(k[j] & 0xFFFFFFFFull);
        float4 pn = pb[nb];
        float ax = -0.5f*pn.x, ay = -0.5f*pn.y, az = -0.5f*pn.z;
        nx += ax; ny += ay; nz += az;
        xx += ax*ax; xy += ax*ay; xz += ax*az;
        yy += ay*ay; yz += ay*az; zz += az*az;
    }
    double* msd = &mstats[(blockIdx.x & (MCOPY-1))*27];
#define RED27(v, i) { float r_ = (v); \
    r_ += __shfl_xor(r_, 1);  r_ += __shfl_xor(r_, 2);  r_ += __shfl_xor(r_, 4); \
    r_ += __shfl_xor(r_, 8);  r_ += __shfl_xor(r_, 16); r_ += __shfl_xor(r_, 32); \
    if (lane == 0) atomicAdd(&msd[i], (double)r_); }
    RED27(nx, 0) RED27(ny, 1) RED27(nz, 2)
    RED27(qx, 3) RED27(qy, 4) RED27(qz, 5)
    RED27(xx, 6) RED27(xy, 7) RED27(xz, 8)
    RED27(yy, 9) RED27(yz, 10) RED27(zz, 11)
    RED27(nx*qx, 12) RED27(nx*qy, 13) RED27(nx*qz, 14)
    RED27(ny*qx, 15) RED27(ny*qy, 16) RED27(ny*qz, 17)
    RED27(nz*qx, 18) RED27(nz*qy, 19) RED27(nz*qz, 20)
    RED27(qx*qx, 21) RED27(qx*qy, 22) RED27(qx*qz, 23)
    RED27(qy*qy, 24) RED27(qy*qz, 25) RED27(qz*qz, 26)
#undef RED27
}

/* split fp32 -> bf16 hi (truncate) + bf16 lo (truncated remainder) */
__device__ __forceinline__ void bsplit(float g, short& hi, short& lo) {
    unsigned bits = __float_as_uint(g);
    unsigned hbits = bits & 0xFFFF0000u;
    float rem = g - __uint_as_float(hbits);
    hi = (short)(bits >> 16);
    lo = (short)(__float_as_uint(rem) >> 16);
}

/* ---------------- K5: main pass — shared-leftover-tile split-bf16 MFMA --------- */
__global__ __launch_bounds__(256) void main_kernel(const int* __restrict__ idxb,
        const int* __restrict__ rankArr, const float4* __restrict__ pts4,
        const double* __restrict__ ms, const float* __restrict__ W1,
        const float* __restrict__ gamma1, const float* __restrict__ beta1,
        const float* __restrict__ W2,
        float* __restrict__ maxbuf, float* __restrict__ stats2f) {
    __shared__ __align__(16) short Thi[4][32*72];
    __shared__ __align__(16) short Tlo[4][32*72];
    __shared__ float chs[128];
    __shared__ float ab1s[128];
    __shared__ double msd[27];
    const int tid = threadIdx.x;
    const int lane = tid & 63;
    const int wv = __builtin_amdgcn_readfirstlane(tid >> 6);
    const int l15 = lane & 15;
    const int quad = lane >> 4;
    if (tid < 128) chs[tid] = 0.f;
    if (tid < 27) {                                /* sum the 32 mstats copies */
        double t = 0.0;
        for (int c = 0; c < MCOPY; ++c) t += ms[c*27 + tid];
        msd[tid] = t;
    }
    __syncthreads();
    if (tid < 64) {                                /* inline fin1m (bn1 affine) */
        int c = tid;
        double wu[3], wvv[3];
#pragma unroll
        for (int i = 0; i < 3; ++i) {
            wu[i] = (double)W1[c*6 + i];
            wvv[i] = (double)W1[c*6 + 3 + i] - wu[i];
        }
        const double S = (double)SAMPLES;
        double mean = (wu[0]*msd[0] + wu[1]*msd[1] + wu[2]*msd[2]
                     + 20.0*(wvv[0]*msd[3] + wvv[1]*msd[4] + wvv[2]*msd[5])) / S;
        double qM1 = wu[0]*wu[0]*msd[6] + wu[1]*wu[1]*msd[9] + wu[2]*wu[2]*msd[11]
                   + 2.0*(wu[0]*wu[1]*msd[7] + wu[0]*wu[2]*msd[8] + wu[1]*wu[2]*msd[10]);
        double cross = 0.0;
#pragma unroll
        for (int i = 0; i < 3; ++i)
#pragma unroll
            for (int j = 0; j < 3; ++j)
                cross += wu[i] * msd[12 + i*3 + j] * wvv[j];
        double qpp = wvv[0]*wvv[0]*msd[21] + wvv[1]*wvv[1]*msd[24] + wvv[2]*wvv[2]*msd[26]
                   + 2.0*(wvv[0]*wvv[1]*msd[22] + wvv[0]*wvv[2]*msd[23] + wvv[1]*wvv[2]*msd[25]);
        double e2 = (qM1 + 2.0*cross + 20.0*qpp) / S;
        double var = e2 - mean*mean;
        float a = (float)((double)gamma1[c] / sqrt(var + (double)EPSF));
        ab1s[c] = a;
        ab1s[64 + c] = beta1[c] - a * (float)mean;
    }
    __syncthreads();

    bf16x8 whi[8], wlo[8];
#pragma unroll
    for (int t = 0; t < 4; ++t)
#pragma unroll
    for (int f = 0; f < 2; ++f) {
        const int o = 16*t + l15;
        const int c0 = 32*f + quad*8;
        const float4* wr = (const float4*)(W2 + o*64 + c0);
        float4 w0 = wr[0], w1 = wr[1];
        float vals[8] = {w0.x,w0.y,w0.z,w0.w,w1.x,w1.y,w1.z,w1.w};
        bf16x8 h, l;
#pragma unroll
        for (int j = 0; j < 8; ++j) { short hj, lj; bsplit(vals[j], hj, lj); h[j]=hj; l[j]=lj; }
        whi[t*2+f] = h; wlo[t*2+f] = l;
    }

    const float w10 = W1[lane*6+0], w11 = W1[lane*6+1], w12 = W1[lane*6+2];
    const float w13 = W1[lane*6+3], w14 = W1[lane*6+4], w15 = W1[lane*6+5];
    const float a1 = ab1s[lane], b1 = ab1s[64 + lane];
    float ssum[4] = {0.f,0.f,0.f,0.f}, ssq[4] = {0.f,0.f,0.f,0.f};
    float lm[4][4];                                /* deferred tile1 max [point][t] */
    short* thi = &Thi[wv][0];
    short* tlo = &Tlo[wv][0];

    const int pt0 = (blockIdx.x * 4 + wv) * 4;
    const int b = pt0 >> 12;
    const float4* pb = pts4 + ((size_t)b << 12);
    const int* rnk = rankArr + ((size_t)b << 12);

    for (int p = 0; p < 4; ++p) {
        const int pt = pt0 + p;
        const float4 pc = pb[pt & (NN - 1)];
        const float X = -0.5f*pc.x, Y = -0.5f*pc.y, Z = -0.5f*pc.z;
        const float vc = (w13 - w10)*X + (w14 - w11)*Y + (w15 - w12)*Z;
        const int srow = rnk[pt & (NN - 1)];       /* uniform scalar lookup */
        const int* irow = idxb + ((size_t)((b << 12) + srow)) * KNN;
#pragma unroll
        for (int k = 0; k < KNN; ++k) {
            float4 pn = pb[irow[k]];
            float nx = -0.5f*pn.x, ny = -0.5f*pn.y, nz = -0.5f*pn.z;
            float uc = w10*nx + w11*ny + w12*nz;
            float g = a1 * (uc + vc) + b1;
            g = fmaxf(g, SLOPE * g);
            short hj, lj; bsplit(g, hj, lj);
            const int row = (k < 16) ? k : (16 + p*4 + (k - 16));
            thi[row*72 + lane] = hj;
            tlo[row*72 + lane] = lj;
        }
        __builtin_amdgcn_wave_barrier();

        bf16x8 ah1[2], al1[2];
#pragma unroll
        for (int f = 0; f < 2; ++f) {
            const int co = 32*f + quad*8;
            ah1[f] = *(const bf16x8*)&thi[l15*72 + co];
            al1[f] = *(const bf16x8*)&tlo[l15*72 + co];
        }

        f32x4 acc1[4];
#pragma unroll
        for (int t = 0; t < 4; ++t) acc1[t] = (f32x4)0.f;
#pragma unroll
        for (int t = 0; t < 4; ++t) {
#pragma unroll
            for (int f = 0; f < 2; ++f) {
                acc1[t] = __builtin_amdgcn_mfma_f32_16x16x32_bf16(ah1[f], whi[t*2+f], acc1[t], 0,0,0);
                acc1[t] = __builtin_amdgcn_mfma_f32_16x16x32_bf16(al1[f], whi[t*2+f], acc1[t], 0,0,0);
                acc1[t] = __builtin_amdgcn_mfma_f32_16x16x32_bf16(ah1[f], wlo[t*2+f], acc1[t], 0,0,0);
            }
        }
        __builtin_amdgcn_wave_barrier();           /* tile1 reads done before next p */

        /* tile1 epilogue: reduce over rows k=0..15 (quads), defer the write */
#pragma unroll
        for (int t = 0; t < 4; ++t) {
            float m1 = fmaxf(fmaxf(acc1[t][0], acc1[t][1]), fmaxf(acc1[t][2], acc1[t][3]));
            float s1 = acc1[t][0] + acc1[t][1] + acc1[t][2] + acc1[t][3];
            float q1 = acc1[t][0]*acc1[t][0] + acc1[t][1]*acc1[t][1]
                     + acc1[t][2]*acc1[t][2] + acc1[t][3]*acc1[t][3];
            m1 = fmaxf(m1, __shfl_xor(m1, 16)); m1 = fmaxf(m1, __shfl_xor(m1, 32));
            s1 += __shfl_xor(s1, 16); s1 += __shfl_xor(s1, 32);
            q1 += __shfl_xor(q1, 16); q1 += __shfl_xor(q1, 32);
            lm[p][t] = m1;
            ssum[t] += s1; ssq[t] += q1;
        }
    }

    /* combined leftover tile: rows = p*4+(k-16), read once, 24 MFMA */
    {
        bf16x8 ah2[2], al2[2];
#pragma unroll
        for (int f = 0; f < 2; ++f) {
            const int co = 32*f + quad*8;
            ah2[f] = *(const bf16x8*)&thi[(16 + l15)*72 + co];
            al2[f] = *(const bf16x8*)&tlo[(16 + l15)*72 + co];
        }
        f32x4 accC[4];
#pragma unroll
        for (int t = 0; t < 4; ++t) accC[t] = (f32x4)0.f;
#pragma unroll
        for (int t = 0; t < 4; ++t) {
#pragma unroll
            for (int f = 0; f < 2; ++f) {
                accC[t] = __builtin_amdgcn_mfma_f32_16x16x32_bf16(ah2[f], whi[t*2+f], accC[t], 0,0,0);
                accC[t] = __builtin_amdgcn_mfma_f32_16x16x32_bf16(al2[f], whi[t*2+f], accC[t], 0,0,0);
                accC[t] = __builtin_amdgcn_mfma_f32_16x16x32_bf16(ah2[f], wlo[t*2+f], accC[t], 0,0,0);
            }
        }
        /* C row = quad*4+reg -> point = quad, k = 16+reg. */
#pragma unroll
        for (int t = 0; t < 4; ++t) {
            float cm = fmaxf(fmaxf(accC[t][0], accC[t][1]), fmaxf(accC[t][2], accC[t][3]));
            float cs = accC[t][0] + accC[t][1] + accC[t][2] + accC[t][3];
            float cq = accC[t][0]*accC[t][0] + accC[t][1]*accC[t][1]
                     + accC[t][2]*accC[t][2] + accC[t][3]*accC[t][3];
            float lmq = (quad == 0) ? lm[0][t] : (quad == 1) ? lm[1][t]
                      : (quad == 2) ? lm[2][t] : lm[3][t];
            maxbuf[((size_t)(pt0 + quad) << 6) + 16*t + l15] = fmaxf(lmq, cm);
            cs += __shfl_xor(cs, 16); cs += __shfl_xor(cs, 32);
            cq += __shfl_xor(cq, 16); cq += __shfl_xor(cq, 32);
            ssum[t] += cs; ssq[t] += cq;
        }
    }

    if (quad == 0) {
#pragma unroll
        for (int t = 0; t < 4; ++t) {
            atomicAdd(&chs[16*t + l15], ssum[t]);
            atomicAdd(&chs[64 + 16*t + l15], ssq[t]);
        }
    }
    __syncthreads();
    if (tid < 128)
        atomicAdd(&stats2f[(blockIdx.x & 1)*128 + tid], chs[tid]);
}

/* ---------------- K7: epilogue — fin2 inlined; transpose + bn2 + lrelu --------- */
__global__ __launch_bounds__(256) void out_kernel(const float* __restrict__ maxbuf,
        const float* __restrict__ s2f, const float* __restrict__ gamma2,
        const float* __restrict__ beta2, float* __restrict__ out) {
    __shared__ float t[64][65];
    __shared__ float ab2s[128];
    const int tid = threadIdx.x;
    if (tid < 64) {                                /* inline fin2 */
        int o = tid;
        double sum = (double)s2f[o] + (double)s2f[128 + o];
        double sq  = (double)s2f[64 + o] + (double)s2f[192 + o];
        double cnt = (double)SAMPLES;
        double mean = sum / cnt;
        double var  = sq / cnt - mean*mean;
        float a = (float)((double)gamma2[o] / sqrt(var + (double)EPSF));
        ab2s[o] = a;
        ab2s[64 + o] = beta2[o] - a * (float)mean;
    }
    const int b = blockIdx.x >> 6;
    const int n0 = (blockIdx.x & 63) << 6;
#pragma unroll
    for (int i = 0; i < 16; ++i) {
        int r = (tid >> 6) + i*4;
        int c = tid & 63;
        t[r][c] = maxbuf[(((size_t)((b << 12) + n0 + r)) << 6) + c];
    }
    __syncthreads();
#pragma unroll
    for (int i = 0; i < 16; ++i) {
        int o = (tid >> 6) + i*4;
        int nn = tid & 63;
        float a = ab2s[o], bb = ab2s[64 + o];
        float h = a * t[nn][o] + bb;
        out[(((size_t)(b*64 + o)) << 12) + n0 + nn] = h >= 0.f ? h : SLOPE*h;
    }
}

extern "C" void kernel_launch(void* const* d_in, const int* in_sizes, int n_in,
                              void* d_out, int out_size, void* d_ws, size_t ws_size,
                              hipStream_t stream) {
    const float* x      = (const float*)d_in[0];
    const float* W1     = (const float*)d_in[1];
    const float* gamma1 = (const float*)d_in[2];
    const float* beta1  = (const float*)d_in[3];
    const float* W2     = (const float*)d_in[4];
    const float* gamma2 = (const float*)d_in[5];
    const float* beta2  = (const float*)d_in[6];
    float* out = (float*)d_out;

    char* ws = (char*)d_ws;
    int*    idxb    = (int*)   (ws + 0);           /* 2,621,440 B (sorted order) */
    float4* pts4    = (float4*)(ws + 2621440);     /* 512 KB */
    float4* sp4     = (float4*)(ws + 3145728);     /* 512 KB sorted pts */
    int*    sidx    = (int*)   (ws + 3670016);     /* 128 KB sorted->orig */
    int*    rankArr = (int*)   (ws + 3801088);     /* 128 KB orig->sorted */
    float*  maxbuf  = (float*) (ws + 19398656);    /* 8,388,608 B, (b,n,o) */
    double* mstats  = (double*)(ws + 27787264);    /* 32x27 doubles = 6912 B */
    float*  stats2f = (float*) (ws + 27794176);    /* 2x128 floats = 1024 B */
    double* zreg    = (double*)(ws + 27787264);    /* zero region: 992 doubles */

    sort_kernel <<<8, 1024, 0, stream>>>(x, pts4, sp4, sidx, rankArr, zreg);
    knn_kernel  <<<512, 256, 0, stream>>>(pts4, sp4, sidx, idxb, mstats);
    main_kernel <<<2048, 256, 0, stream>>>(idxb, rankArr, pts4, mstats, W1, gamma1,
                                           beta1, W2, maxbuf, stats2f);
    out_kernel  <<<512, 256, 0, stream>>>(maxbuf, stats2f, gamma2, beta2, out);
}

// Round 6
// 391.806 us; speedup vs baseline: 1.9854x; 1.0357x over previous
//
#include <hip/hip_runtime.h>
#include <hip/hip_bf16.h>
#include <math.h>

#define BB 8
#define NN 4096
#define KNN 20
#define CH 64
#define SAMPLES (BB*NN*KNN)   /* 655360 */
#define EPSF 1e-5f
#define SLOPE 0.2f
#define MCOPY 32              /* mstats copies to spread atomic contention */
#define WBCAP 24              /* per-wave per-lane buffer entries (guard at >=8, +16/eval16) */
#define SENTD 17592186044416.0  /* 2^44: sorts after every real key (enc*4096+idx < 2^44) */

typedef float f32x4 __attribute__((ext_vector_type(4)));
typedef short bf16x8 __attribute__((ext_vector_type(8)));
typedef unsigned long long ull;

/* decode order-preserving uint back to float */
__device__ __forceinline__ float key_decode(unsigned e) {
    return __uint_as_float((e & 0x80000000u) ? (e ^ 0x80000000u) : ~e);
}

/* ---------------- K0: per-batch: build pts4 + bitonic sort by x + zero stats --- */
__global__ __launch_bounds__(1024) void sort_kernel(const float* __restrict__ x,
        float4* __restrict__ pts4, float4* __restrict__ sp4, int* __restrict__ sidx,
        int* __restrict__ rankArr, double* __restrict__ zreg) {
#pragma clang fp contract(off)
    __shared__ unsigned long long S[NN];                     /* 32 KB */
    const int tid = threadIdx.x;
    const int b = blockIdx.x;
    if (b == 0 && tid < 992) zreg[tid] = 0.0;     /* mstats(864d) + stats2f(128d) */
    const float* xb = x + (size_t)b * 3 * NN;
    for (int i = tid; i < NN; i += 1024) {
        float mx = xb[i], my = xb[NN + i], mz = xb[2*NN + i];
        float sq = mx*mx; sq += my*my; sq += mz*mz;          /* ref summation order */
        pts4[(b << 12) + i] = make_float4(-2.0f*mx, -2.0f*my, -2.0f*mz, sq);
        unsigned uu = __float_as_uint(mx);
        unsigned e = uu ^ (((unsigned)((int)uu >> 31)) | 0x80000000u);
        S[i] = ((unsigned long long)e << 32) | (unsigned)i;
    }
    __syncthreads();
    for (int k = 2; k <= NN; k <<= 1) {
        for (int j = k >> 1; j > 0; j >>= 1) {
#pragma unroll
            for (int tt = 0; tt < 2; ++tt) {
                int t = tid + tt*1024;            /* 2048 pairs */
                int i = ((t & ~(j - 1)) << 1) | (t & (j - 1));
                int h = i | j;
                unsigned long long a = S[i], c = S[h];
                bool up = ((i & k) == 0);
                if ((a > c) == up) { S[i] = c; S[h] = a; }
            }
            __syncthreads();
        }
    }
    for (int s = tid; s < NN; s += 1024) {
        int oi = (int)(unsigned)(S[s] & 0xFFFFFFFFu);
        float mx = xb[oi], my = xb[NN + oi], mz = xb[2*NN + oi];  /* recompute: no RAW */
        float sq = mx*mx; sq += my*my; sq += mz*mz;
        sp4[(b << 12) + s] = make_float4(-2.0f*mx, -2.0f*my, -2.0f*mz, sq);
        sidx[(b << 12) + s] = oi;
        rankArr[(b << 12) + oi] = s;
    }
}

/* ---------------- K1: exact KNN — transposed (1 lane = 1 query), 4-wave split,
   f64-packed keys + warm-start sharing.
   Key = enc(d)*4096 + idx: exact in f64 mantissa; f64 order == (enc,idx) u64
   order (idx < 4096).  Sorted-20 maintenance = fmin/fmax bubble network
   (40 instr vs ~100 for the u64 select network).
   Wave 0 evaluates the home chunk first and posts per-lane k[19] to LDS;
   waves 1-3 warm-start their thresholds from it (k-lists stay empty -> merge
   sources remain disjoint, no duplicate keys).  Chunk ownership (disjoint,
   monotone-in-x): w0: home + r0+128,+256..; w1: r0+64,+192..; w2: r0-64,..;
   w3: r0-128,..  Thresholds are conservative upper bounds at all times ->
   prune/filter never drop a true neighbor; exactness from buffered exact-key
   inserts (same fmaf filter + margin M, same exact-d ref-parenthesization,
   same (enc,idx) ordering as the verified rounds). */

__device__ __forceinline__ float rlf(float v, int l) {
    return __uint_as_float((unsigned)__builtin_amdgcn_readlane((int)__float_as_uint(v), l));
}

/* branchless sorted insert into ascending k[0..19] (drops old k[19]):
   bubble network, 2 instr/position (v_min_f64/v_max_f64) */
__device__ __forceinline__ void insert20d(double (&k)[20], const double key) {
    double c = key;
#pragma unroll
    for (int i = 0; i < 20; ++i) {
        const double mi = k[i];
        k[i] = fmin(mi, c);
        c = fmax(mi, c);
    }
}

__device__ __forceinline__ void refreshd(const double k19,
        float& kthd, const float sqn, float& M, float& thr) {
#pragma clang fp contract(off)
    if (k19 < SENTD) {
        const unsigned e19 = (unsigned)(k19 * (1.0/4096.0));   /* exact trunc */
        kthd = key_decode(e19);
    } else kthd = INFINITY;                        /* list not yet full */
    M = 1e-3f*(fabsf(kthd) + fabsf(sqn) + 1.0f);
    thr = (kthd - sqn) + M;
}

__device__ __forceinline__ void flush20d(double* buf, const int lane, int& cnt,
        double (&k)[20], float& kthd, const float sqn, float& M, float& thr) {
#pragma clang fp contract(off)
    double key = buf[lane];                       /* j=0 prefetched */
    int j = 0;
    while (__any(j < cnt)) {
        double keyn = buf[((j + 1) << 6) + lane]; /* hide LDS latency */
        const bool acc = (j < cnt) && (key < k[19]);
        if (__any(acc)) { if (acc) insert20d(k, key); }
        key = keyn; ++j;
    }
    cnt = 0;
    refreshd(k[19], kthd, sqn, M, thr);
}

/* evaluate 16 candidates of register chunk C/Ci; DIR<0 walks t descending so
   left chunks are processed nearest-first (threshold tightens fastest). */
template<int T0, int DIR>
__device__ __forceinline__ void eval16(const float4 C, const int Ci, double* buf,
        const int lane, const float qx, const float qy, const float qz,
        const float sqn, const float thr, int& cnt) {
#pragma clang fp contract(off)
#pragma unroll
    for (int u = 0; u < 16; ++u) {
        const int t = (DIR > 0) ? (T0 + u) : (T0 + 15 - u);
        const float px = rlf(C.x, t);
        const float py = rlf(C.y, t);
        const float pz = rlf(C.z, t);
        const float pw = rlf(C.w, t);
        const float sc = fmaf(px, qx, fmaf(py, qy, fmaf(pz, qz, pw)));
        const bool push = sc <= thr;
        if (__any(push)) {
            const int pidx = __builtin_amdgcn_readlane(Ci, t);
            const float mx = -0.5f*px, my = -0.5f*py, mz = -0.5f*pz;
            float inner = qx*mx; inner += qy*my; inner += qz*mz;
            const float d = (sqn - 2.0f*inner) + pw;    /* ref parenthesization */
            const unsigned uu = __float_as_uint(d);
            const unsigned e = uu ^ (((unsigned)((int)uu >> 31)) | 0x80000000u);
            const double keyv = fma((double)e, 4096.0, (double)(unsigned)pidx);
            if (push) { buf[(cnt << 6) + lane] = keyv; ++cnt; }
        }
    }
}

/* scan the arithmetic chunk sequence s, s+DIR*128, ... within [0, NN-64] */
template<int DIR>
__device__ __forceinline__ void scan(const float4* __restrict__ sb,
        const int* __restrict__ si, int s, double (&k)[20], double* buf,
        const int lane, const float qx, const float qy, const float qz,
        const float sqn, float& kthd, float& M, float& thr, int& cnt) {
#pragma clang fp contract(off)
    if (s < 0 || s > NN - 64) return;
    float4 C = sb[s + lane];
    int Ci = si[s + lane];
    while (true) {
        /* prune vs nearest slot of current chunk */
        const float xn = rlf(C.x, (DIR > 0) ? 0 : 63);
        const float dx = (DIR > 0) ? ((-0.5f*xn) - qx) : (qx - (-0.5f*xn));
        if (__all(dx*dx > kthd + M)) break;
        const int s2 = s + DIR*128;
        const bool more = (s2 >= 0) && (s2 <= NN - 64);
        float4 Cn; int Cin = 0;
        if (more) { Cn = sb[s2 + lane]; Cin = si[s2 + lane]; }  /* prefetch */
        if (DIR > 0) {
            eval16<0,1> (C, Ci, buf, lane, qx,qy,qz,sqn, thr, cnt);
            if (__any(cnt >= 8)) flush20d(buf, lane, cnt, k, kthd, sqn, M, thr);
            eval16<16,1>(C, Ci, buf, lane, qx,qy,qz,sqn, thr, cnt);
            if (__any(cnt >= 8)) flush20d(buf, lane, cnt, k, kthd, sqn, M, thr);
            eval16<32,1>(C, Ci, buf, lane, qx,qy,qz,sqn, thr, cnt);
            if (__any(cnt >= 8)) flush20d(buf, lane, cnt, k, kthd, sqn, M, thr);
            eval16<48,1>(C, Ci, buf, lane, qx,qy,qz,sqn, thr, cnt);
        } else {
            eval16<48,-1>(C, Ci, buf, lane, qx,qy,qz,sqn, thr, cnt);
            if (__any(cnt >= 8)) flush20d(buf, lane, cnt, k, kthd, sqn, M, thr);
            eval16<32,-1>(C, Ci, buf, lane, qx,qy,qz,sqn, thr, cnt);
            if (__any(cnt >= 8)) flush20d(buf, lane, cnt, k, kthd, sqn, M, thr);
            eval16<16,-1>(C, Ci, buf, lane, qx,qy,qz,sqn, thr, cnt);
            if (__any(cnt >= 8)) flush20d(buf, lane, cnt, k, kthd, sqn, M, thr);
            eval16<0,-1> (C, Ci, buf, lane, qx,qy,qz,sqn, thr, cnt);
        }
        flush20d(buf, lane, cnt, k, kthd, sqn, M, thr);  /* refresh for prune */
        if (!more) break;
        C = Cn; Ci = Cin; s = s2;
    }
}

__global__ __launch_bounds__(256) void knn_kernel(const float4* __restrict__ pts4,
        const float4* __restrict__ sp4, const int* __restrict__ sidx,
        int* __restrict__ idx_out, double* __restrict__ mstats) {
#pragma clang fp contract(off)
    __shared__ double BUF[4][WBCAP*64];           /* 48 KB */
    __shared__ double KSH[64];                    /* wave0 home k19 share */

    const int tid  = threadIdx.x;
    const int lane = tid & 63;
    const int w    = tid >> 6;
    const int Q0 = blockIdx.x << 6;               /* global sorted rank base */
    const int b  = Q0 >> 12;
    const int r0 = Q0 & (NN - 1);                 /* multiple of 64 */
    const float4* sb = sp4 + ((size_t)b << 12);
    const int*    si = sidx + ((size_t)b << 12);

    /* lane's own query IS slot `lane` of the home chunk */
    const float4 R0 = sb[r0 + lane];
    const float qx = -0.5f*R0.x, qy = -0.5f*R0.y, qz = -0.5f*R0.z;
    const float sqn = R0.w;

    double k[20];
#pragma unroll
    for (int j = 0; j < 20; ++j) k[j] = SENTD;
    float kthd = INFINITY, M = INFINITY, thr = INFINITY;
    int cnt = 0;
    double* buf = &BUF[w][0];

    if (w == 0) {                                 /* home chunk: exact prefill */
        const int Ri0 = si[r0 + lane];
        eval16<0,1> (R0, Ri0, buf, lane, qx,qy,qz,sqn, thr, cnt);
        if (__any(cnt >= 8)) flush20d(buf, lane, cnt, k, kthd, sqn, M, thr);
        eval16<16,1>(R0, Ri0, buf, lane, qx,qy,qz,sqn, thr, cnt);
        if (__any(cnt >= 8)) flush20d(buf, lane, cnt, k, kthd, sqn, M, thr);
        eval16<32,1>(R0, Ri0, buf, lane, qx,qy,qz,sqn, thr, cnt);
        if (__any(cnt >= 8)) flush20d(buf, lane, cnt, k, kthd, sqn, M, thr);
        eval16<48,1>(R0, Ri0, buf, lane, qx,qy,qz,sqn, thr, cnt);
        flush20d(buf, lane, cnt, k, kthd, sqn, M, thr);
        KSH[lane] = k[19];                        /* exact home 20th key */
    }
    __syncthreads();
    if (w != 0)                                   /* warm-start threshold only */
        refreshd(KSH[lane], kthd, sqn, M, thr);

    /* disjoint side sequences (wave0 continues right after home) */
    if      (w == 0) scan< 1>(sb, si, r0 + 128, k, buf, lane, qx,qy,qz,sqn, kthd, M, thr, cnt);
    else if (w == 1) scan< 1>(sb, si, r0 + 64,  k, buf, lane, qx,qy,qz,sqn, kthd, M, thr, cnt);
    else if (w == 2) scan<-1>(sb, si, r0 - 64,  k, buf, lane, qx,qy,qz,sqn, kthd, M, thr, cnt);
    else             scan<-1>(sb, si, r0 - 128, k, buf, lane, qx,qy,qz,sqn, kthd, M, thr, cnt);
    flush20d(buf, lane, cnt, k, kthd, sqn, M, thr);        /* final drain */

    if (w != 0) {                                 /* post sorted list */
#pragma unroll
        for (int j = 0; j < KNN; ++j) buf[(j << 6) + lane] = k[j];
    }
    __syncthreads();
    if (w != 0) return;

    /* merge waves 1..3 (disjoint candidate sets: no duplicate keys).
       Sorted sources -> early-out when all lanes reject. */
#pragma unroll 1
    for (int w2 = 1; w2 < 4; ++w2) {
        double* src = &BUF[w2][0];
#pragma unroll 1
        for (int j = 0; j < KNN; ++j) {
            const double key = src[(j << 6) + lane];
            const bool acc = key < k[19];
            if (__all(!acc)) break;
            if (acc) insert20d(k, key);
        }
    }

    /* transpose top-20 idx through LDS (reuse wave0 BUF) for coalesced writes */
    unsigned* TB = (unsigned*)&BUF[0][0];
    __builtin_amdgcn_wave_barrier();
#pragma unroll
    for (int j = 0; j < KNN; ++j) {
        const double kj = k[j];
        const unsigned e = (unsigned)(kj * (1.0/4096.0));
        TB[lane*21 + j] = (unsigned)(kj - (double)e * 4096.0);   /* exact idx */
    }
    __builtin_amdgcn_wave_barrier();
    int* iout = idx_out + (size_t)Q0 * KNN;
#pragma unroll
    for (int u = 0; u < KNN; ++u) {
        int g = (u << 6) + lane;                  /* 1280 contiguous ints */
        iout[g] = (int)TB[(g / KNN)*21 + (g % KNN)];
    }

    /* moments epilogue: each lane sums over its own 20 neighbors */
    const float4* pb = pts4 + ((size_t)b << 12);
    float nx=0.f, ny=0.f, nz=0.f, xx=0.f, xy=0.f, xz=0.f, yy=0.f, yz=0.f, zz=0.f;
#pragma unroll
    for (int j = 0; j < KNN; ++j) {
        const double kj = k[j];
        const unsigned e = (unsigned)(kj * (1.0/4096.0));
        const int nb = (int)(unsigned)(kj - (double)e * 4096.0);
        float4 pn = pb[nb];
        float ax = -0.5f*pn.x, ay = -0.5f*pn.y, az = -0.5f*pn.z;
        nx += ax; ny += ay; nz += az;
        xx += ax*ax; xy += ax*ay; xz += ax*az;
        yy += ay*ay; yz += ay*az; zz += az*az;
    }
    double* msd = &mstats[(blockIdx.x & (MCOPY-1))*27];
#define RED27(v, i) { float r_ = (v); \
    r_ += __shfl_xor(r_, 1);  r_ += __shfl_xor(r_, 2);  r_ += __shfl_xor(r_, 4); \
    r_ += __shfl_xor(r_, 8);  r_ += __shfl_xor(r_, 16); r_ += __shfl_xor(r_, 32); \
    if (lane == 0) atomicAdd(&msd[i], (double)r_); }
    RED27(nx, 0) RED27(ny, 1) RED27(nz, 2)
    RED27(qx, 3) RED27(qy, 4) RED27(qz, 5)
    RED27(xx, 6) RED27(xy, 7) RED27(xz, 8)
    RED27(yy, 9) RED27(yz, 10) RED27(zz, 11)
    RED27(nx*qx, 12) RED27(nx*qy, 13) RED27(nx*qz, 14)
    RED27(ny*qx, 15) RED27(ny*qy, 16) RED27(ny*qz, 17)
    RED27(nz*qx, 18) RED27(nz*qy, 19) RED27(nz*qz, 20)
    RED27(qx*qx, 21) RED27(qx*qy, 22) RED27(qx*qz, 23)
    RED27(qy*qy, 24) RED27(qy*qz, 25) RED27(qz*qz, 26)
#undef RED27
}

/* split fp32 -> bf16 hi (truncate) + bf16 lo (truncated remainder) */
__device__ __forceinline__ void bsplit(float g, short& hi, short& lo) {
    unsigned bits = __float_as_uint(g);
    unsigned hbits = bits & 0xFFFF0000u;
    float rem = g - __uint_as_float(hbits);
    hi = (short)(bits >> 16);
    lo = (short)(__float_as_uint(rem) >> 16);
}

/* ---------------- K5: main pass — shared-leftover-tile split-bf16 MFMA --------- */
__global__ __launch_bounds__(256) void main_kernel(const int* __restrict__ idxb,
        const int* __restrict__ rankArr, const float4* __restrict__ pts4,
        const double* __restrict__ ms, const float* __restrict__ W1,
        const float* __restrict__ gamma1, const float* __restrict__ beta1,
        const float* __restrict__ W2,
        float* __restrict__ maxbuf, float* __restrict__ stats2f) {
    __shared__ __align__(16) short Thi[4][32*72];
    __shared__ __align__(16) short Tlo[4][32*72];
    __shared__ float chs[128];
    __shared__ float ab1s[128];
    __shared__ double msd[27];
    const int tid = threadIdx.x;
    const int lane = tid & 63;
    const int wv = __builtin_amdgcn_readfirstlane(tid >> 6);
    const int l15 = lane & 15;
    const int quad = lane >> 4;
    if (tid < 128) chs[tid] = 0.f;
    if (tid < 27) {                                /* sum the 32 mstats copies */
        double t = 0.0;
        for (int c = 0; c < MCOPY; ++c) t += ms[c*27 + tid];
        msd[tid] = t;
    }
    __syncthreads();
    if (tid < 64) {                                /* inline fin1m (bn1 affine) */
        int c = tid;
        double wu[3], wvv[3];
#pragma unroll
        for (int i = 0; i < 3; ++i) {
            wu[i] = (double)W1[c*6 + i];
            wvv[i] = (double)W1[c*6 + 3 + i] - wu[i];
        }
        const double S = (double)SAMPLES;
        double mean = (wu[0]*msd[0] + wu[1]*msd[1] + wu[2]*msd[2]
                     + 20.0*(wvv[0]*msd[3] + wvv[1]*msd[4] + wvv[2]*msd[5])) / S;
        double qM1 = wu[0]*wu[0]*msd[6] + wu[1]*wu[1]*msd[9] + wu[2]*wu[2]*msd[11]
                   + 2.0*(wu[0]*wu[1]*msd[7] + wu[0]*wu[2]*msd[8] + wu[1]*wu[2]*msd[10]);
        double cross = 0.0;
#pragma unroll
        for (int i = 0; i < 3; ++i)
#pragma unroll
            for (int j = 0; j < 3; ++j)
                cross += wu[i] * msd[12 + i*3 + j] * wvv[j];
        double qpp = wvv[0]*wvv[0]*msd[21] + wvv[1]*wvv[1]*msd[24] + wvv[2]*wvv[2]*msd[26]
                   + 2.0*(wvv[0]*wvv[1]*msd[22] + wvv[0]*wvv[2]*msd[23] + wvv[1]*wvv[2]*msd[25]);
        double e2 = (qM1 + 2.0*cross + 20.0*qpp) / S;
        double var = e2 - mean*mean;
        float a = (float)((double)gamma1[c] / sqrt(var + (double)EPSF));
        ab1s[c] = a;
        ab1s[64 + c] = beta1[c] - a * (float)mean;
    }
    __syncthreads();

    bf16x8 whi[8], wlo[8];
#pragma unroll
    for (int t = 0; t < 4; ++t)
#pragma unroll
    for (int f = 0; f < 2; ++f) {
        const int o = 16*t + l15;
        const int c0 = 32*f + quad*8;
        const float4* wr = (const float4*)(W2 + o*64 + c0);
        float4 w0 = wr[0], w1 = wr[1];
        float vals[8] = {w0.x,w0.y,w0.z,w0.w,w1.x,w1.y,w1.z,w1.w};
        bf16x8 h, l;
#pragma unroll
        for (int j = 0; j < 8; ++j) { short hj, lj; bsplit(vals[j], hj, lj); h[j]=hj; l[j]=lj; }
        whi[t*2+f] = h; wlo[t*2+f] = l;
    }

    const float w10 = W1[lane*6+0], w11 = W1[lane*6+1], w12 = W1[lane*6+2];
    const float w13 = W1[lane*6+3], w14 = W1[lane*6+4], w15 = W1[lane*6+5];
    const float a1 = ab1s[lane], b1 = ab1s[64 + lane];
    float ssum[4] = {0.f,0.f,0.f,0.f}, ssq[4] = {0.f,0.f,0.f,0.f};
    float lm[4][4];                                /* deferred tile1 max [point][t] */
    short* thi = &Thi[wv][0];
    short* tlo = &Tlo[wv][0];

    const int pt0 = (blockIdx.x * 4 + wv) * 4;
    const int b = pt0 >> 12;
    const float4* pb = pts4 + ((size_t)b << 12);
    const int* rnk = rankArr + ((size_t)b << 12);

    for (int p = 0; p < 4; ++p) {
        const int pt = pt0 + p;
        const float4 pc = pb[pt & (NN - 1)];
        const float X = -0.5f*pc.x, Y = -0.5f*pc.y, Z = -0.5f*pc.z;
        const float vc = (w13 - w10)*X + (w14 - w11)*Y + (w15 - w12)*Z;
        const int srow = rnk[pt & (NN - 1)];       /* uniform scalar lookup */
        const int* irow = idxb + ((size_t)((b << 12) + srow)) * KNN;
#pragma unroll
        for (int k = 0; k < KNN; ++k) {
            float4 pn = pb[irow[k]];
            float nx = -0.5f*pn.x, ny = -0.5f*pn.y, nz = -0.5f*pn.z;
            float uc = w10*nx + w11*ny + w12*nz;
            float g = a1 * (uc + vc) + b1;
            g = fmaxf(g, SLOPE * g);
            short hj, lj; bsplit(g, hj, lj);
            const int row = (k < 16) ? k : (16 + p*4 + (k - 16));
            thi[row*72 + lane] = hj;
            tlo[row*72 + lane] = lj;
        }
        __builtin_amdgcn_wave_barrier();

        bf16x8 ah1[2], al1[2];
#pragma unroll
        for (int f = 0; f < 2; ++f) {
            const int co = 32*f + quad*8;
            ah1[f] = *(const bf16x8*)&thi[l15*72 + co];
            al1[f] = *(const bf16x8*)&tlo[l15*72 + co];
        }

        f32x4 acc1[4];
#pragma unroll
        for (int t = 0; t < 4; ++t) acc1[t] = (f32x4)0.f;
#pragma unroll
        for (int t = 0; t < 4; ++t) {
#pragma unroll
            for (int f = 0; f < 2; ++f) {
                acc1[t] = __builtin_amdgcn_mfma_f32_16x16x32_bf16(ah1[f], whi[t*2+f], acc1[t], 0,0,0);
                acc1[t] = __builtin_amdgcn_mfma_f32_16x16x32_bf16(al1[f], whi[t*2+f], acc1[t], 0,0,0);
                acc1[t] = __builtin_amdgcn_mfma_f32_16x16x32_bf16(ah1[f], wlo[t*2+f], acc1[t], 0,0,0);
            }
        }
        __builtin_amdgcn_wave_barrier();           /* tile1 reads done before next p */

        /* tile1 epilogue: reduce over rows k=0..15 (quads), defer the write */
#pragma unroll
        for (int t = 0; t < 4; ++t) {
            float m1 = fmaxf(fmaxf(acc1[t][0], acc1[t][1]), fmaxf(acc1[t][2], acc1[t][3]));
            float s1 = acc1[t][0] + acc1[t][1] + acc1[t][2] + acc1[t][3];
            float q1 = acc1[t][0]*acc1[t][0] + acc1[t][1]*acc1[t][1]
                     + acc1[t][2]*acc1[t][2] + acc1[t][3]*acc1[t][3];
            m1 = fmaxf(m1, __shfl_xor(m1, 16)); m1 = fmaxf(m1, __shfl_xor(m1, 32));
            s1 += __shfl_xor(s1, 16); s1 += __shfl_xor(s1, 32);
            q1 += __shfl_xor(q1, 16); q1 += __shfl_xor(q1, 32);
            lm[p][t] = m1;
            ssum[t] += s1; ssq[t] += q1;
        }
    }

    /* combined leftover tile: rows = p*4+(k-16), read once, 24 MFMA */
    {
        bf16x8 ah2[2], al2[2];
#pragma unroll
        for (int f = 0; f < 2; ++f) {
            const int co = 32*f + quad*8;
            ah2[f] = *(const bf16x8*)&thi[(16 + l15)*72 + co];
            al2[f] = *(const bf16x8*)&tlo[(16 + l15)*72 + co];
        }
        f32x4 accC[4];
#pragma unroll
        for (int t = 0; t < 4; ++t) accC[t] = (f32x4)0.f;
#pragma unroll
        for (int t = 0; t < 4; ++t) {
#pragma unroll
            for (int f = 0; f < 2; ++f) {
                accC[t] = __builtin_amdgcn_mfma_f32_16x16x32_bf16(ah2[f], whi[t*2+f], accC[t], 0,0,0);
                accC[t] = __builtin_amdgcn_mfma_f32_16x16x32_bf16(al2[f], whi[t*2+f], accC[t], 0,0,0);
                accC[t] = __builtin_amdgcn_mfma_f32_16x16x32_bf16(ah2[f], wlo[t*2+f], accC[t], 0,0,0);
            }
        }
        /* C row = quad*4+reg -> point = quad, k = 16+reg. */
#pragma unroll
        for (int t = 0; t < 4; ++t) {
            float cm = fmaxf(fmaxf(accC[t][0], accC[t][1]), fmaxf(accC[t][2], accC[t][3]));
            float cs = accC[t][0] + accC[t][1] + accC[t][2] + accC[t][3];
            float cq = accC[t][0]*accC[t][0] + accC[t][1]*accC[t][1]
                     + accC[t][2]*accC[t][2] + accC[t][3]*accC[t][3];
            float lmq = (quad == 0) ? lm[0][t] : (quad == 1) ? lm[1][t]
                      : (quad == 2) ? lm[2][t] : lm[3][t];
            maxbuf[((size_t)(pt0 + quad) << 6) + 16*t + l15] = fmaxf(lmq, cm);
            cs += __shfl_xor(cs, 16); cs += __shfl_xor(cs, 32);
            cq += __shfl_xor(cq, 16); cq += __shfl_xor(cq, 32);
            ssum[t] += cs; ssq[t] += cq;
        }
    }

    if (quad == 0) {
#pragma unroll
        for (int t = 0; t < 4; ++t) {
            atomicAdd(&chs[16*t + l15], ssum[t]);
            atomicAdd(&chs[64 + 16*t + l15], ssq[t]);
        }
    }
    __syncthreads();
    if (tid < 128)
        atomicAdd(&stats2f[(blockIdx.x & 1)*128 + tid], chs[tid]);
}

/* ---------------- K7: epilogue — fin2 inlined; transpose + bn2 + lrelu --------- */
__global__ __launch_bounds__(256) void out_kernel(const float* __restrict__ maxbuf,
        const float* __restrict__ s2f, const float* __restrict__ gamma2,
        const float* __restrict__ beta2, float* __restrict__ out) {
    __shared__ float t[64][65];
    __shared__ float ab2s[128];
    const int tid = threadIdx.x;
    if (tid < 64) {                                /* inline fin2 */
        int o = tid;
        double sum = (double)s2f[o] + (double)s2f[128 + o];
        double sq  = (double)s2f[64 + o] + (double)s2f[192 + o];
        double cnt = (double)SAMPLES;
        double mean = sum / cnt;
        double var  = sq / cnt - mean*mean;
        float a = (float)((double)gamma2[o] / sqrt(var + (double)EPSF));
        ab2s[o] = a;
        ab2s[64 + o] = beta2[o] - a * (float)mean;
    }
    const int b = blockIdx.x >> 6;
    const int n0 = (blockIdx.x & 63) << 6;
#pragma unroll
    for (int i = 0; i < 16; ++i) {
        int r = (tid >> 6) + i*4;
        int c = tid & 63;
        t[r][c] = maxbuf[(((size_t)((b << 12) + n0 + r)) << 6) + c];
    }
    __syncthreads();
#pragma unroll
    for (int i = 0; i < 16; ++i) {
        int o = (tid >> 6) + i*4;
        int nn = tid & 63;
        float a = ab2s[o], bb = ab2s[64 + o];
        float h = a * t[nn][o] + bb;
        out[(((size_t)(b*64 + o)) << 12) + n0 + nn] = h >= 0.f ? h : SLOPE*h;
    }
}

extern "C" void kernel_launch(void* const* d_in, const int* in_sizes, int n_in,
                              void* d_out, int out_size, void* d_ws, size_t ws_size,
                              hipStream_t stream) {
    const float* x      = (const float*)d_in[0];
    const float* W1     = (const float*)d_in[1];
    const float* gamma1 = (const float*)d_in[2];
    const float* beta1  = (const float*)d_in[3];
    const float* W2     = (const float*)d_in[4];
    const float* gamma2 = (const float*)d_in[5];
    const float* beta2  = (const float*)d_in[6];
    float* out = (float*)d_out;

    char* ws = (char*)d_ws;
    int*    idxb    = (int*)   (ws + 0);           /* 2,621,440 B (sorted order) */
    float4* pts4    = (float4*)(ws + 2621440);     /* 512 KB */
    float4* sp4     = (float4*)(ws + 3145728);     /* 512 KB sorted pts */
    int*    sidx    = (int*)   (ws + 3670016);     /* 128 KB sorted->orig */
    int*    rankArr = (int*)   (ws + 3801088);     /* 128 KB orig->sorted */
    float*  maxbuf  = (float*) (ws + 19398656);    /* 8,388,608 B, (b,n,o) */
    double* mstats  = (double*)(ws + 27787264);    /* 32x27 doubles = 6912 B */
    float*  stats2f = (float*) (ws + 27794176);    /* 2x128 floats = 1024 B */
    double* zreg    = (double*)(ws + 27787264);    /* zero region: 992 doubles */

    sort_kernel <<<8, 1024, 0, stream>>>(x, pts4, sp4, sidx, rankArr, zreg);
    knn_kernel  <<<512, 256, 0, stream>>>(pts4, sp4, sidx, idxb, mstats);
    main_kernel <<<2048, 256, 0, stream>>>(idxb, rankArr, pts4, mstats, W1, gamma1,
                                           beta1, W2, maxbuf, stats2f);
    out_kernel  <<<512, 256, 0, stream>>>(maxbuf, stats2f, gamma2, beta2, out);
}

// Round 7
// 384.371 us; speedup vs baseline: 2.0238x; 1.0193x over previous
//
#include <hip/hip_runtime.h>
#include <hip/hip_bf16.h>
#include <math.h>

#define BB 8
#define NN 4096
#define KNN 20
#define CH 64
#define SAMPLES (BB*NN*KNN)   /* 655360 */
#define EPSF 1e-5f
#define SLOPE 0.2f
#define MCOPY 32              /* mstats copies to spread atomic contention */
#define WBCAP 24              /* per-wave per-lane buffer entries (guard at >=8, +16/eval16) */
#define SENTD 17592186044416.0  /* 2^44: sorts after every real key (enc*4096+idx < 2^44) */

typedef float f32x4 __attribute__((ext_vector_type(4)));
typedef short bf16x8 __attribute__((ext_vector_type(8)));
typedef unsigned long long ull;

/* decode order-preserving uint back to float */
__device__ __forceinline__ float key_decode(unsigned e) {
    return __uint_as_float((e & 0x80000000u) ? (e ^ 0x80000000u) : ~e);
}

/* ---------------- K0: per-batch: build pts4 + bitonic sort by x + zero stats --- */
__global__ __launch_bounds__(1024) void sort_kernel(const float* __restrict__ x,
        float4* __restrict__ pts4, float4* __restrict__ sp4, int* __restrict__ sidx,
        int* __restrict__ rankArr, double* __restrict__ zreg) {
#pragma clang fp contract(off)
    __shared__ unsigned long long S[NN];                     /* 32 KB */
    const int tid = threadIdx.x;
    const int b = blockIdx.x;
    if (b == 0 && tid < 992) zreg[tid] = 0.0;     /* mstats(864d) + stats2f(128d) */
    const float* xb = x + (size_t)b * 3 * NN;
    for (int i = tid; i < NN; i += 1024) {
        float mx = xb[i], my = xb[NN + i], mz = xb[2*NN + i];
        float sq = mx*mx; sq += my*my; sq += mz*mz;          /* ref summation order */
        pts4[(b << 12) + i] = make_float4(-2.0f*mx, -2.0f*my, -2.0f*mz, sq);
        unsigned uu = __float_as_uint(mx);
        unsigned e = uu ^ (((unsigned)((int)uu >> 31)) | 0x80000000u);
        S[i] = ((unsigned long long)e << 32) | (unsigned)i;
    }
    __syncthreads();
    for (int k = 2; k <= NN; k <<= 1) {
        for (int j = k >> 1; j > 0; j >>= 1) {
#pragma unroll
            for (int tt = 0; tt < 2; ++tt) {
                int t = tid + tt*1024;            /* 2048 pairs */
                int i = ((t & ~(j - 1)) << 1) | (t & (j - 1));
                int h = i | j;
                unsigned long long a = S[i], c = S[h];
                bool up = ((i & k) == 0);
                if ((a > c) == up) { S[i] = c; S[h] = a; }
            }
            __syncthreads();
        }
    }
    for (int s = tid; s < NN; s += 1024) {
        int oi = (int)(unsigned)(S[s] & 0xFFFFFFFFu);
        float mx = xb[oi], my = xb[NN + oi], mz = xb[2*NN + oi];  /* recompute: no RAW */
        float sq = mx*mx; sq += my*my; sq += mz*mz;
        sp4[(b << 12) + s] = make_float4(-2.0f*mx, -2.0f*my, -2.0f*mz, sq);
        sidx[(b << 12) + s] = oi;
        rankArr[(b << 12) + oi] = s;
    }
}

/* ---------------- K1: exact KNN — transposed (1 lane = 1 query), 4-wave split,
   f64-packed keys + PERSISTENT warm bound.
   kthd_eff = min(own k19 when full, kwarm from home chunk).  Both are upper
   bounds on the lane's FINAL 20th distance, so filtering/pruning with
   kthd_eff + M is conservative: no true neighbor dropped.  Side waves post
   "top-20 of own subset truncated to keys < bound" (rest SENTD) — exact for
   the merge since truncated keys can't enter the global top-20.
   Everything else identical to the verified rounds: same fmaf filter +
   margin M, same exact-d ref-parenthesization, same (enc,idx) ordering. */

__device__ __forceinline__ float rlf(float v, int l) {
    return __uint_as_float((unsigned)__builtin_amdgcn_readlane((int)__float_as_uint(v), l));
}

/* branchless sorted insert into ascending k[0..19] (drops old k[19]):
   bubble network, 2 instr/position (v_min_f64/v_max_f64) */
__device__ __forceinline__ void insert20d(double (&k)[20], const double key) {
    double c = key;
#pragma unroll
    for (int i = 0; i < 20; ++i) {
        const double mi = k[i];
        k[i] = fmin(mi, c);
        c = fmax(mi, c);
    }
}

__device__ __forceinline__ float kdecd(const double k19) {
    if (k19 < SENTD) {
        const unsigned e19 = (unsigned)(k19 * (1.0/4096.0));   /* exact trunc */
        return key_decode(e19);
    }
    return INFINITY;
}

__device__ __forceinline__ void refreshd(const double k19, const float kwarm,
        float& kthd, const float sqn, float& M, float& thr) {
#pragma clang fp contract(off)
    kthd = fminf(kdecd(k19), kwarm);              /* persistent warm floor */
    M = 1e-3f*(fabsf(kthd) + fabsf(sqn) + 1.0f);
    thr = (kthd - sqn) + M;
}

__device__ __forceinline__ void flush20d(double* buf, const int lane, int& cnt,
        double (&k)[20], const float kwarm, float& kthd, const float sqn,
        float& M, float& thr) {
#pragma clang fp contract(off)
    double key = buf[lane];                       /* j=0 prefetched */
    int j = 0;
    while (__any(j < cnt)) {
        double keyn = buf[((j + 1) << 6) + lane]; /* hide LDS latency */
        const bool acc = (j < cnt) && (key < k[19]);
        if (__any(acc)) { if (acc) insert20d(k, key); }
        key = keyn; ++j;
    }
    cnt = 0;
    refreshd(k[19], kwarm, kthd, sqn, M, thr);
}

/* evaluate 16 candidates of register chunk C/Ci; DIR<0 walks t descending so
   left chunks are processed nearest-first (threshold tightens fastest). */
template<int T0, int DIR>
__device__ __forceinline__ void eval16(const float4 C, const int Ci, double* buf,
        const int lane, const float qx, const float qy, const float qz,
        const float sqn, const float thr, int& cnt) {
#pragma clang fp contract(off)
#pragma unroll
    for (int u = 0; u < 16; ++u) {
        const int t = (DIR > 0) ? (T0 + u) : (T0 + 15 - u);
        const float px = rlf(C.x, t);
        const float py = rlf(C.y, t);
        const float pz = rlf(C.z, t);
        const float pw = rlf(C.w, t);
        const float sc = fmaf(px, qx, fmaf(py, qy, fmaf(pz, qz, pw)));
        const bool push = sc <= thr;
        if (__any(push)) {
            const int pidx = __builtin_amdgcn_readlane(Ci, t);
            const float mx = -0.5f*px, my = -0.5f*py, mz = -0.5f*pz;
            float inner = qx*mx; inner += qy*my; inner += qz*mz;
            const float d = (sqn - 2.0f*inner) + pw;    /* ref parenthesization */
            const unsigned uu = __float_as_uint(d);
            const unsigned e = uu ^ (((unsigned)((int)uu >> 31)) | 0x80000000u);
            const double keyv = fma((double)e, 4096.0, (double)(unsigned)pidx);
            if (push) { buf[(cnt << 6) + lane] = keyv; ++cnt; }
        }
    }
}

/* scan the arithmetic chunk sequence s, s+DIR*128, ... within [0, NN-64] */
template<int DIR>
__device__ __forceinline__ void scan(const float4* __restrict__ sb,
        const int* __restrict__ si, int s, double (&k)[20], double* buf,
        const int lane, const float qx, const float qy, const float qz,
        const float sqn, const float kwarm, float& kthd, float& M, float& thr,
        int& cnt) {
#pragma clang fp contract(off)
    if (s < 0 || s > NN - 64) return;
    float4 C = sb[s + lane];
    int Ci = si[s + lane];
    while (true) {
        /* prune vs nearest slot of current chunk */
        const float xn = rlf(C.x, (DIR > 0) ? 0 : 63);
        const float dx = (DIR > 0) ? ((-0.5f*xn) - qx) : (qx - (-0.5f*xn));
        if (__all(dx*dx > kthd + M)) break;
        const int s2 = s + DIR*128;
        const bool more = (s2 >= 0) && (s2 <= NN - 64);
        float4 Cn; int Cin = 0;
        if (more) { Cn = sb[s2 + lane]; Cin = si[s2 + lane]; }  /* prefetch */
        if (DIR > 0) {
            eval16<0,1> (C, Ci, buf, lane, qx,qy,qz,sqn, thr, cnt);
            if (__any(cnt >= 8)) flush20d(buf, lane, cnt, k, kwarm, kthd, sqn, M, thr);
            eval16<16,1>(C, Ci, buf, lane, qx,qy,qz,sqn, thr, cnt);
            if (__any(cnt >= 8)) flush20d(buf, lane, cnt, k, kwarm, kthd, sqn, M, thr);
            eval16<32,1>(C, Ci, buf, lane, qx,qy,qz,sqn, thr, cnt);
            if (__any(cnt >= 8)) flush20d(buf, lane, cnt, k, kwarm, kthd, sqn, M, thr);
            eval16<48,1>(C, Ci, buf, lane, qx,qy,qz,sqn, thr, cnt);
        } else {
            eval16<48,-1>(C, Ci, buf, lane, qx,qy,qz,sqn, thr, cnt);
            if (__any(cnt >= 8)) flush20d(buf, lane, cnt, k, kwarm, kthd, sqn, M, thr);
            eval16<32,-1>(C, Ci, buf, lane, qx,qy,qz,sqn, thr, cnt);
            if (__any(cnt >= 8)) flush20d(buf, lane, cnt, k, kwarm, kthd, sqn, M, thr);
            eval16<16,-1>(C, Ci, buf, lane, qx,qy,qz,sqn, thr, cnt);
            if (__any(cnt >= 8)) flush20d(buf, lane, cnt, k, kwarm, kthd, sqn, M, thr);
            eval16<0,-1> (C, Ci, buf, lane, qx,qy,qz,sqn, thr, cnt);
        }
        flush20d(buf, lane, cnt, k, kwarm, kthd, sqn, M, thr); /* refresh+prune */
        if (!more) break;
        C = Cn; Ci = Cin; s = s2;
    }
}

__global__ __launch_bounds__(256) void knn_kernel(const float4* __restrict__ pts4,
        const float4* __restrict__ sp4, const int* __restrict__ sidx,
        int* __restrict__ idx_out, double* __restrict__ mstats) {
#pragma clang fp contract(off)
    __shared__ double BUF[4][WBCAP*64];           /* 48 KB */
    __shared__ double KSH[64];                    /* wave0 home k19 share */

    const int tid  = threadIdx.x;
    const int lane = tid & 63;
    const int w    = tid >> 6;
    const int Q0 = blockIdx.x << 6;               /* global sorted rank base */
    const int b  = Q0 >> 12;
    const int r0 = Q0 & (NN - 1);                 /* multiple of 64 */
    const float4* sb = sp4 + ((size_t)b << 12);
    const int*    si = sidx + ((size_t)b << 12);

    /* lane's own query IS slot `lane` of the home chunk */
    const float4 R0 = sb[r0 + lane];
    const float qx = -0.5f*R0.x, qy = -0.5f*R0.y, qz = -0.5f*R0.z;
    const float sqn = R0.w;

    double k[20];
#pragma unroll
    for (int j = 0; j < 20; ++j) k[j] = SENTD;
    float kthd = INFINITY, M = INFINITY, thr = INFINITY;
    float kwarm = INFINITY;
    int cnt = 0;
    double* buf = &BUF[w][0];

    if (w == 0) {                                 /* home chunk: exact prefill */
        const int Ri0 = si[r0 + lane];
        eval16<0,1> (R0, Ri0, buf, lane, qx,qy,qz,sqn, thr, cnt);
        if (__any(cnt >= 8)) flush20d(buf, lane, cnt, k, kwarm, kthd, sqn, M, thr);
        eval16<16,1>(R0, Ri0, buf, lane, qx,qy,qz,sqn, thr, cnt);
        if (__any(cnt >= 8)) flush20d(buf, lane, cnt, k, kwarm, kthd, sqn, M, thr);
        eval16<32,1>(R0, Ri0, buf, lane, qx,qy,qz,sqn, thr, cnt);
        if (__any(cnt >= 8)) flush20d(buf, lane, cnt, k, kwarm, kthd, sqn, M, thr);
        eval16<48,1>(R0, Ri0, buf, lane, qx,qy,qz,sqn, thr, cnt);
        flush20d(buf, lane, cnt, k, kwarm, kthd, sqn, M, thr);
        KSH[lane] = k[19];                        /* exact home 20th key */
    }
    __syncthreads();
    kwarm = kdecd(KSH[lane]);                     /* persistent warm bound */
    if (w != 0)
        refreshd(SENTD, kwarm, kthd, sqn, M, thr);

    /* disjoint side sequences (wave0 continues right after home) */
    if      (w == 0) scan< 1>(sb, si, r0 + 128, k, buf, lane, qx,qy,qz,sqn, kwarm, kthd, M, thr, cnt);
    else if (w == 1) scan< 1>(sb, si, r0 + 64,  k, buf, lane, qx,qy,qz,sqn, kwarm, kthd, M, thr, cnt);
    else if (w == 2) scan<-1>(sb, si, r0 - 64,  k, buf, lane, qx,qy,qz,sqn, kwarm, kthd, M, thr, cnt);
    else             scan<-1>(sb, si, r0 - 128, k, buf, lane, qx,qy,qz,sqn, kwarm, kthd, M, thr, cnt);
    flush20d(buf, lane, cnt, k, kwarm, kthd, sqn, M, thr); /* final drain */

    if (w != 0) {                                 /* post sorted (truncated) list */
#pragma unroll
        for (int j = 0; j < KNN; ++j) buf[(j << 6) + lane] = k[j];
    }
    __syncthreads();
    if (w != 0) return;

    /* merge waves 1..3 (disjoint candidate sets: no duplicate keys).
       Sorted sources -> early-out when all lanes reject. */
#pragma unroll 1
    for (int w2 = 1; w2 < 4; ++w2) {
        double* src = &BUF[w2][0];
#pragma unroll 1
        for (int j = 0; j < KNN; ++j) {
            const double key = src[(j << 6) + lane];
            const bool acc = key < k[19];
            if (__all(!acc)) break;
            if (acc) insert20d(k, key);
        }
    }

    /* transpose top-20 idx through LDS (reuse wave0 BUF) for coalesced writes */
    unsigned* TB = (unsigned*)&BUF[0][0];
    __builtin_amdgcn_wave_barrier();
#pragma unroll
    for (int j = 0; j < KNN; ++j) {
        const double kj = k[j];
        const unsigned e = (unsigned)(kj * (1.0/4096.0));
        TB[lane*21 + j] = (unsigned)(kj - (double)e * 4096.0);   /* exact idx */
    }
    __builtin_amdgcn_wave_barrier();
    int* iout = idx_out + (size_t)Q0 * KNN;
#pragma unroll
    for (int u = 0; u < KNN; ++u) {
        int g = (u << 6) + lane;                  /* 1280 contiguous ints */
        iout[g] = (int)TB[(g / KNN)*21 + (g % KNN)];
    }

    /* moments epilogue: each lane sums over its own 20 neighbors */
    const float4* pb = pts4 + ((size_t)b << 12);
    float nx=0.f, ny=0.f, nz=0.f, xx=0.f, xy=0.f, xz=0.f, yy=0.f, yz=0.f, zz=0.f;
#pragma unroll
    for (int j = 0; j < KNN; ++j) {
        const double kj = k[j];
        const unsigned e = (unsigned)(kj * (1.0/4096.0));
        const int nb = (int)(unsigned)(kj - (double)e * 4096.0);
        float4 pn = pb[nb];
        float ax = -0.5f*pn.x, ay = -0.5f*pn.y, az = -0.5f*pn.z;
        nx += ax; ny += ay; nz += az;
        xx += ax*ax; xy += ax*ay; xz += ax*az;
        yy += ay*ay; yz += ay*az; zz += az*az;
    }
    double* msd = &mstats[(blockIdx.x & (MCOPY-1))*27];
#define RED27(v, i) { float r_ = (v); \
    r_ += __shfl_xor(r_, 1);  r_ += __shfl_xor(r_, 2);  r_ += __shfl_xor(r_, 4); \
    r_ += __shfl_xor(r_, 8);  r_ += __shfl_xor(r_, 16); r_ += __shfl_xor(r_, 32); \
    if (lane == 0) atomicAdd(&msd[i], (double)r_); }
    RED27(nx, 0) RED27(ny, 1) RED27(nz, 2)
    RED27(qx, 3) RED27(qy, 4) RED27(qz, 5)
    RED27(xx, 6) RED27(xy, 7) RED27(xz, 8)
    RED27(yy, 9) RED27(yz, 10) RED27(zz, 11)
    RED27(nx*qx, 12) RED27(nx*qy, 13) RED27(nx*qz, 14)
    RED27(ny*qx, 15) RED27(ny*qy, 16) RED27(ny*qz, 17)
    RED27(nz*qx, 18) RED27(nz*qy, 19) RED27(nz*qz, 20)
    RED27(qx*qx, 21) RED27(qx*qy, 22) RED27(qx*qz, 23)
    RED27(qy*qy, 24) RED27(qy*qz, 25) RED27(qz*qz, 26)
#undef RED27
}

/* split fp32 -> bf16 hi (truncate) + bf16 lo (truncated remainder) */
__device__ __forceinline__ void bsplit(float g, short& hi, short& lo) {
    unsigned bits = __float_as_uint(g);
    unsigned hbits = bits & 0xFFFF0000u;
    float rem = g - __uint_as_float(hbits);
    hi = (short)(bits >> 16);
    lo = (short)(__float_as_uint(rem) >> 16);
}

/* ---------------- K5: main pass — shared-leftover-tile split-bf16 MFMA --------- */
__global__ __launch_bounds__(256) void main_kernel(const int* __restrict__ idxb,
        const int* __restrict__ rankArr, const float4* __restrict__ pts4,
        const double* __restrict__ ms, const float* __restrict__ W1,
        const float* __restrict__ gamma1, const float* __restrict__ beta1,
        const float* __restrict__ W2,
        float* __restrict__ maxbuf, float* __restrict__ stats2f) {
    __shared__ __align__(16) short Thi[4][32*72];
    __shared__ __align__(16) short Tlo[4][32*72];
    __shared__ float chs[128];
    __shared__ float ab1s[128];
    __shared__ double msd[27];
    const int tid = threadIdx.x;
    const int lane = tid & 63;
    const int wv = __builtin_amdgcn_readfirstlane(tid >> 6);
    const int l15 = lane & 15;
    const int quad = lane >> 4;
    if (tid < 128) chs[tid] = 0.f;
    if (tid < 27) {                                /* sum the 32 mstats copies */
        double t = 0.0;
        for (int c = 0; c < MCOPY; ++c) t += ms[c*27 + tid];
        msd[tid] = t;
    }
    __syncthreads();
    if (tid < 64) {                                /* inline fin1m (bn1 affine) */
        int c = tid;
        double wu[3], wvv[3];
#pragma unroll
        for (int i = 0; i < 3; ++i) {
            wu[i] = (double)W1[c*6 + i];
            wvv[i] = (double)W1[c*6 + 3 + i] - wu[i];
        }
        const double S = (double)SAMPLES;
        double mean = (wu[0]*msd[0] + wu[1]*msd[1] + wu[2]*msd[2]
                     + 20.0*(wvv[0]*msd[3] + wvv[1]*msd[4] + wvv[2]*msd[5])) / S;
        double qM1 = wu[0]*wu[0]*msd[6] + wu[1]*wu[1]*msd[9] + wu[2]*wu[2]*msd[11]
                   + 2.0*(wu[0]*wu[1]*msd[7] + wu[0]*wu[2]*msd[8] + wu[1]*wu[2]*msd[10]);
        double cross = 0.0;
#pragma unroll
        for (int i = 0; i < 3; ++i)
#pragma unroll
            for (int j = 0; j < 3; ++j)
                cross += wu[i] * msd[12 + i*3 + j] * wvv[j];
        double qpp = wvv[0]*wvv[0]*msd[21] + wvv[1]*wvv[1]*msd[24] + wvv[2]*wvv[2]*msd[26]
                   + 2.0*(wvv[0]*wvv[1]*msd[22] + wvv[0]*wvv[2]*msd[23] + wvv[1]*wvv[2]*msd[25]);
        double e2 = (qM1 + 2.0*cross + 20.0*qpp) / S;
        double var = e2 - mean*mean;
        float a = (float)((double)gamma1[c] / sqrt(var + (double)EPSF));
        ab1s[c] = a;
        ab1s[64 + c] = beta1[c] - a * (float)mean;
    }
    __syncthreads();

    bf16x8 whi[8], wlo[8];
#pragma unroll
    for (int t = 0; t < 4; ++t)
#pragma unroll
    for (int f = 0; f < 2; ++f) {
        const int o = 16*t + l15;
        const int c0 = 32*f + quad*8;
        const float4* wr = (const float4*)(W2 + o*64 + c0);
        float4 w0 = wr[0], w1 = wr[1];
        float vals[8] = {w0.x,w0.y,w0.z,w0.w,w1.x,w1.y,w1.z,w1.w};
        bf16x8 h, l;
#pragma unroll
        for (int j = 0; j < 8; ++j) { short hj, lj; bsplit(vals[j], hj, lj); h[j]=hj; l[j]=lj; }
        whi[t*2+f] = h; wlo[t*2+f] = l;
    }

    const float w10 = W1[lane*6+0], w11 = W1[lane*6+1], w12 = W1[lane*6+2];
    const float w13 = W1[lane*6+3], w14 = W1[lane*6+4], w15 = W1[lane*6+5];
    const float a1 = ab1s[lane], b1 = ab1s[64 + lane];
    float ssum[4] = {0.f,0.f,0.f,0.f}, ssq[4] = {0.f,0.f,0.f,0.f};
    float lm[4][4];                                /* deferred tile1 max [point][t] */
    short* thi = &Thi[wv][0];
    short* tlo = &Tlo[wv][0];

    const int pt0 = (blockIdx.x * 4 + wv) * 4;
    const int b = pt0 >> 12;
    const float4* pb = pts4 + ((size_t)b << 12);
    const int* rnk = rankArr + ((size_t)b << 12);

    for (int p = 0; p < 4; ++p) {
        const int pt = pt0 + p;
        const float4 pc = pb[pt & (NN - 1)];
        const float X = -0.5f*pc.x, Y = -0.5f*pc.y, Z = -0.5f*pc.z;
        const float vc = (w13 - w10)*X + (w14 - w11)*Y + (w15 - w12)*Z;
        const int srow = rnk[pt & (NN - 1)];       /* uniform scalar lookup */
        const int* irow = idxb + ((size_t)((b << 12) + srow)) * KNN;
#pragma unroll
        for (int k = 0; k < KNN; ++k) {
            float4 pn = pb[irow[k]];
            float nx = -0.5f*pn.x, ny = -0.5f*pn.y, nz = -0.5f*pn.z;
            float uc = w10*nx + w11*ny + w12*nz;
            float g = a1 * (uc + vc) + b1;
            g = fmaxf(g, SLOPE * g);
            short hj, lj; bsplit(g, hj, lj);
            const int row = (k < 16) ? k : (16 + p*4 + (k - 16));
            thi[row*72 + lane] = hj;
            tlo[row*72 + lane] = lj;
        }
        __builtin_amdgcn_wave_barrier();

        bf16x8 ah1[2], al1[2];
#pragma unroll
        for (int f = 0; f < 2; ++f) {
            const int co = 32*f + quad*8;
            ah1[f] = *(const bf16x8*)&thi[l15*72 + co];
            al1[f] = *(const bf16x8*)&tlo[l15*72 + co];
        }

        f32x4 acc1[4];
#pragma unroll
        for (int t = 0; t < 4; ++t) acc1[t] = (f32x4)0.f;
#pragma unroll
        for (int t = 0; t < 4; ++t) {
#pragma unroll
            for (int f = 0; f < 2; ++f) {
                acc1[t] = __builtin_amdgcn_mfma_f32_16x16x32_bf16(ah1[f], whi[t*2+f], acc1[t], 0,0,0);
                acc1[t] = __builtin_amdgcn_mfma_f32_16x16x32_bf16(al1[f], whi[t*2+f], acc1[t], 0,0,0);
                acc1[t] = __builtin_amdgcn_mfma_f32_16x16x32_bf16(ah1[f], wlo[t*2+f], acc1[t], 0,0,0);
            }
        }
        __builtin_amdgcn_wave_barrier();           /* tile1 reads done before next p */

        /* tile1 epilogue: reduce over rows k=0..15 (quads), defer the write */
#pragma unroll
        for (int t = 0; t < 4; ++t) {
            float m1 = fmaxf(fmaxf(acc1[t][0], acc1[t][1]), fmaxf(acc1[t][2], acc1[t][3]));
            float s1 = acc1[t][0] + acc1[t][1] + acc1[t][2] + acc1[t][3];
            float q1 = acc1[t][0]*acc1[t][0] + acc1[t][1]*acc1[t][1]
                     + acc1[t][2]*acc1[t][2] + acc1[t][3]*acc1[t][3];
            m1 = fmaxf(m1, __shfl_xor(m1, 16)); m1 = fmaxf(m1, __shfl_xor(m1, 32));
            s1 += __shfl_xor(s1, 16); s1 += __shfl_xor(s1, 32);
            q1 += __shfl_xor(q1, 16); q1 += __shfl_xor(q1, 32);
            lm[p][t] = m1;
            ssum[t] += s1; ssq[t] += q1;
        }
    }

    /* combined leftover tile: rows = p*4+(k-16), read once, 24 MFMA */
    {
        bf16x8 ah2[2], al2[2];
#pragma unroll
        for (int f = 0; f < 2; ++f) {
            const int co = 32*f + quad*8;
            ah2[f] = *(const bf16x8*)&thi[(16 + l15)*72 + co];
            al2[f] = *(const bf16x8*)&tlo[(16 + l15)*72 + co];
        }
        f32x4 accC[4];
#pragma unroll
        for (int t = 0; t < 4; ++t) accC[t] = (f32x4)0.f;
#pragma unroll
        for (int t = 0; t < 4; ++t) {
#pragma unroll
            for (int f = 0; f < 2; ++f) {
                accC[t] = __builtin_amdgcn_mfma_f32_16x16x32_bf16(ah2[f], whi[t*2+f], accC[t], 0,0,0);
                accC[t] = __builtin_amdgcn_mfma_f32_16x16x32_bf16(al2[f], whi[t*2+f], accC[t], 0,0,0);
                accC[t] = __builtin_amdgcn_mfma_f32_16x16x32_bf16(ah2[f], wlo[t*2+f], accC[t], 0,0,0);
            }
        }
        /* C row = quad*4+reg -> point = quad, k = 16+reg. */
#pragma unroll
        for (int t = 0; t < 4; ++t) {
            float cm = fmaxf(fmaxf(accC[t][0], accC[t][1]), fmaxf(accC[t][2], accC[t][3]));
            float cs = accC[t][0] + accC[t][1] + accC[t][2] + accC[t][3];
            float cq = accC[t][0]*accC[t][0] + accC[t][1]*accC[t][1]
                     + accC[t][2]*accC[t][2] + accC[t][3]*accC[t][3];
            float lmq = (quad == 0) ? lm[0][t] : (quad == 1) ? lm[1][t]
                      : (quad == 2) ? lm[2][t] : lm[3][t];
            maxbuf[((size_t)(pt0 + quad) << 6) + 16*t + l15] = fmaxf(lmq, cm);
            cs += __shfl_xor(cs, 16); cs += __shfl_xor(cs, 32);
            cq += __shfl_xor(cq, 16); cq += __shfl_xor(cq, 32);
            ssum[t] += cs; ssq[t] += cq;
        }
    }

    if (quad == 0) {
#pragma unroll
        for (int t = 0; t < 4; ++t) {
            atomicAdd(&chs[16*t + l15], ssum[t]);
            atomicAdd(&chs[64 + 16*t + l15], ssq[t]);
        }
    }
    __syncthreads();
    if (tid < 128)
        atomicAdd(&stats2f[(blockIdx.x & 1)*128 + tid], chs[tid]);
}

/* ---------------- K7: epilogue — fin2 inlined; transpose + bn2 + lrelu --------- */
__global__ __launch_bounds__(256) void out_kernel(const float* __restrict__ maxbuf,
        const float* __restrict__ s2f, const float* __restrict__ gamma2,
        const float* __restrict__ beta2, float* __restrict__ out) {
    __shared__ float t[64][65];
    __shared__ float ab2s[128];
    const int tid = threadIdx.x;
    if (tid < 64) {                                /* inline fin2 */
        int o = tid;
        double sum = (double)s2f[o] + (double)s2f[128 + o];
        double sq  = (double)s2f[64 + o] + (double)s2f[192 + o];
        double cnt = (double)SAMPLES;
        double mean = sum / cnt;
        double var  = sq / cnt - mean*mean;
        float a = (float)((double)gamma2[o] / sqrt(var + (double)EPSF));
        ab2s[o] = a;
        ab2s[64 + o] = beta2[o] - a * (float)mean;
    }
    const int b = blockIdx.x >> 6;
    const int n0 = (blockIdx.x & 63) << 6;
#pragma unroll
    for (int i = 0; i < 16; ++i) {
        int r = (tid >> 6) + i*4;
        int c = tid & 63;
        t[r][c] = maxbuf[(((size_t)((b << 12) + n0 + r)) << 6) + c];
    }
    __syncthreads();
#pragma unroll
    for (int i = 0; i < 16; ++i) {
        int o = (tid >> 6) + i*4;
        int nn = tid & 63;
        float a = ab2s[o], bb = ab2s[64 + o];
        float h = a * t[nn][o] + bb;
        out[(((size_t)(b*64 + o)) << 12) + n0 + nn] = h >= 0.f ? h : SLOPE*h;
    }
}

extern "C" void kernel_launch(void* const* d_in, const int* in_sizes, int n_in,
                              void* d_out, int out_size, void* d_ws, size_t ws_size,
                              hipStream_t stream) {
    const float* x      = (const float*)d_in[0];
    const float* W1     = (const float*)d_in[1];
    const float* gamma1 = (const float*)d_in[2];
    const float* beta1  = (const float*)d_in[3];
    const float* W2     = (const float*)d_in[4];
    const float* gamma2 = (const float*)d_in[5];
    const float* beta2  = (const float*)d_in[6];
    float* out = (float*)d_out;

    char* ws = (char*)d_ws;
    int*    idxb    = (int*)   (ws + 0);           /* 2,621,440 B (sorted order) */
    float4* pts4    = (float4*)(ws + 2621440);     /* 512 KB */
    float4* sp4     = (float4*)(ws + 3145728);     /* 512 KB sorted pts */
    int*    sidx    = (int*)   (ws + 3670016);     /* 128 KB sorted->orig */
    int*    rankArr = (int*)   (ws + 3801088);     /* 128 KB orig->sorted */
    float*  maxbuf  = (float*) (ws + 19398656);    /* 8,388,608 B, (b,n,o) */
    double* mstats  = (double*)(ws + 27787264);    /* 32x27 doubles = 6912 B */
    float*  stats2f = (float*) (ws + 27794176);    /* 2x128 floats = 1024 B */
    double* zreg    = (double*)(ws + 27787264);    /* zero region: 992 doubles */

    sort_kernel <<<8, 1024, 0, stream>>>(x, pts4, sp4, sidx, rankArr, zreg);
    knn_kernel  <<<512, 256, 0, stream>>>(pts4, sp4, sidx, idxb, mstats);
    main_kernel <<<2048, 256, 0, stream>>>(idxb, rankArr, pts4, mstats, W1, gamma1,
                                           beta1, W2, maxbuf, stats2f);
    out_kernel  <<<512, 256, 0, stream>>>(maxbuf, stats2f, gamma2, beta2, out);
}

// Round 8
// 257.989 us; speedup vs baseline: 3.0152x; 1.4899x over previous
//
#include <hip/hip_runtime.h>
#include <hip/hip_bf16.h>
#include <math.h>

#define BB 8
#define NN 4096
#define KNN 20
#define CH 64
#define SAMPLES (BB*NN*KNN)   /* 655360 */
#define EPSF 1e-5f
#define SLOPE 0.2f
#define MCOPY 32              /* mstats copies to spread atomic contention */

typedef float f32x4 __attribute__((ext_vector_type(4)));
typedef short bf16x8 __attribute__((ext_vector_type(8)));

/* decode order-preserving uint back to float */
__device__ __forceinline__ float key_decode(unsigned e) {
    return __uint_as_float((e & 0x80000000u) ? (e ^ 0x80000000u) : ~e);
}

/* rank-select flush: merge ovf[0..cnt) + inc[0..19] -> new exact top-20 in inc. */
__device__ __forceinline__ void rank_flush(unsigned long long* ovf,
                                           unsigned long long* inc,
                                           unsigned long long* scr,
                                           int& cnt, float& kthd, int lane) {
    while (cnt > 0) {
        int take = cnt < 44 ? cnt : 44;
        unsigned long long key;
        if (lane < take)      key = ovf[cnt - take + lane];
        else if (lane >= 44)  key = inc[lane - 44];
        else                  key = ~0ull;
        scr[lane] = key;
        __builtin_amdgcn_wave_barrier();
        int r = 0;
#pragma unroll
        for (int t = 0; t < 64; ++t) {
            unsigned long long kt = scr[t];       /* uniform addr -> broadcast */
            r += (kt < key) ? 1 : 0;
        }
        __builtin_amdgcn_wave_barrier();
        if (r < KNN) inc[r] = key;                /* padding ranks land >= 20 */
        __builtin_amdgcn_wave_barrier();
        kthd = key_decode((unsigned)(inc[KNN-1] >> 32));
        cnt -= take;
    }
}

/* ---------------- K0: per-batch: build pts4 + bitonic sort by x + zero stats --- */
__global__ __launch_bounds__(1024) void sort_kernel(const float* __restrict__ x,
        float4* __restrict__ pts4, float4* __restrict__ sp4, int* __restrict__ sidx,
        int* __restrict__ rankArr, double* __restrict__ zreg) {
#pragma clang fp contract(off)
    __shared__ unsigned long long S[NN];                     /* 32 KB */
    const int tid = threadIdx.x;
    const int b = blockIdx.x;
    if (b == 0 && tid < 992) zreg[tid] = 0.0;     /* mstats(864d) + stats2f(128d) */
    const float* xb = x + (size_t)b * 3 * NN;
    for (int i = tid; i < NN; i += 1024) {
        float mx = xb[i], my = xb[NN + i], mz = xb[2*NN + i];
        float sq = mx*mx; sq += my*my; sq += mz*mz;          /* ref summation order */
        pts4[(b << 12) + i] = make_float4(-2.0f*mx, -2.0f*my, -2.0f*mz, sq);
        unsigned uu = __float_as_uint(mx);
        unsigned e = uu ^ (((unsigned)((int)uu >> 31)) | 0x80000000u);
        S[i] = ((unsigned long long)e << 32) | (unsigned)i;
    }
    __syncthreads();
    for (int k = 2; k <= NN; k <<= 1) {
        for (int j = k >> 1; j > 0; j >>= 1) {
#pragma unroll
            for (int tt = 0; tt < 2; ++tt) {
                int t = tid + tt*1024;            /* 2048 pairs */
                int i = ((t & ~(j - 1)) << 1) | (t & (j - 1));
                int h = i | j;
                unsigned long long a = S[i], c = S[h];
                bool up = ((i & k) == 0);
                if ((a > c) == up) { S[i] = c; S[h] = a; }
            }
            __syncthreads();
        }
    }
    for (int s = tid; s < NN; s += 1024) {
        int oi = (int)(unsigned)(S[s] & 0xFFFFFFFFu);
        float mx = xb[oi], my = xb[NN + oi], mz = xb[2*NN + oi];  /* recompute: no RAW */
        float sq = mx*mx; sq += my*my; sq += mz*mz;
        sp4[(b << 12) + s] = make_float4(-2.0f*mx, -2.0f*my, -2.0f*mz, sq);
        sidx[(b << 12) + s] = oi;
        rankArr[(b << 12) + oi] = s;
    }
}

/* ---------------- K1: exact KNN — pipelined sorted sweep + moments epilogue.
   Both sides' chunk data AND boundary x are prefetched one iteration ahead,
   breaking the serial load->check->load chain. idx_out at sorted rank. -------- */
__global__ __launch_bounds__(256) void knn_kernel(const float4* __restrict__ pts4,
        const float4* __restrict__ sp4, const int* __restrict__ sidx,
        int* __restrict__ idx_out, double* __restrict__ mstats) {
#pragma clang fp contract(off)
    __shared__ unsigned long long OVF[4][160];               /* 5 KB   */
    __shared__ unsigned long long INC[4][24];
    __shared__ unsigned long long SCR[4][64];
    __shared__ float MOM[4][27];
    const int tid = threadIdx.x;
    const int lane = tid & 63;
    const int wv = __builtin_amdgcn_readfirstlane(tid >> 6);
    const int s = blockIdx.x * 4 + wv;                       /* sorted-rank query */
    const int b = s >> 12;
    const int ss = s & (NN - 1);
    const float4* sb = sp4 + ((size_t)b << 12);
    const int* si = sidx + ((size_t)b << 12);
    unsigned long long* ovf = &OVF[wv][0];
    unsigned long long* inc = &INC[wv][0];
    unsigned long long* scr = &SCR[wv][0];

    const float4 Qc = sb[ss];
    const float qx = -0.5f*Qc.x, qy = -0.5f*Qc.y, qz = -0.5f*Qc.z; /* exact coords */
    const float sqn = Qc.w;
    int c0 = ss - 32; c0 = c0 < 0 ? 0 : (c0 > NN-64 ? NN-64 : c0);
    float kthd, thr, M;
    int cnt = 0;

    /* prefill: exact d for the 64 nearest-in-x, rank-select directly */
    {
        const float4 P = sb[c0 + lane];
        const float mx = -0.5f*P.x, my = -0.5f*P.y, mz = -0.5f*P.z;
        float inner = qx*mx; inner += qy*my; inner += qz*mz;
        const float d = (sqn - 2.0f*inner) + P.w;            /* ref parenthesization */
        unsigned uu = __float_as_uint(d);
        unsigned e = uu ^ (((unsigned)((int)uu >> 31)) | 0x80000000u);
        unsigned long long key = ((unsigned long long)e << 32) | (unsigned)si[c0 + lane];
        scr[lane] = key;
        __builtin_amdgcn_wave_barrier();
        int r = 0;
#pragma unroll
        for (int t = 0; t < 64; ++t) {
            unsigned long long kt = scr[t];
            r += (kt < key) ? 1 : 0;
        }
        __builtin_amdgcn_wave_barrier();
        if (r < KNN) inc[r] = key;
        __builtin_amdgcn_wave_barrier();
        kthd = key_decode((unsigned)(inc[KNN-1] >> 32));
        M = 1e-3f*(fabsf(kthd) + fabsf(sqn) + 1.0f);
        thr = (kthd - sqn) + M;
    }

    int lo = c0, hi = c0 + 64;
    bool dl = (lo == 0), dr = (hi == NN);

    /* prime the pipeline: chunk data + boundary x for each live side */
    float4 PL, PR;
    float xL = 0.f, xR = 0.f;
    if (!dl) {
        int st = lo - 64; st = st < 0 ? 0 : st;
        PL = sb[st + lane];                        /* st+63 <= lo-1 < NN */
        xL = sb[lo - 1].x;
    }
    if (!dr) {
        int sI = hi + lane;
        PR = sb[sI < NN-1 ? sI : NN-1];
        xR = sb[hi].x;
    }

    while (!dl || !dr) {
        bool goL = false, goR = false;
        if (!dl) {                                 /* checks on PREFETCHED x: no stall */
            const float dx = qx - (-0.5f*xL);
            goL = (dx*dx <= kthd + M);
            if (!goL) dl = true;
        }
        if (!dr) {
            const float dx = (-0.5f*xR) - qx;
            goR = (dx*dx <= kthd + M);
            if (!goR) dr = true;
        }
        const int stL = (lo - 64) < 0 ? 0 : (lo - 64);
        const int enR = (hi + 64) > NN ? NN : (hi + 64);

        /* issue next-iteration prefetches before doing any work */
        float4 PLn = PL, PRn = PR;
        float xLn = 0.f, xRn = 0.f;
        if (goL && stL > 0) {
            int st2 = stL - 64; st2 = st2 < 0 ? 0 : st2;
            PLn = sb[st2 + lane];
            xLn = sb[stL - 1].x;
        }
        if (goR && enR < NN) {
            int sI = enR + lane;
            PRn = sb[sI < NN-1 ? sI : NN-1];
            xRn = sb[enR].x;
        }

        if (cnt > 32) {                            /* LDS flush overlaps the loads */
            rank_flush(ovf, inc, scr, cnt, kthd, lane);
            M = 1e-3f*(fabsf(kthd) + fabsf(sqn) + 1.0f);
            thr = (kthd - sqn) + M;
        }

        if (goL) {
            const int sI = stL + lane;
            const bool valid = sI < lo;
            const float sc = fmaf(PL.x, qx, fmaf(PL.y, qy, fmaf(PL.z, qz, PL.w)));
            bool push = valid && (sc <= thr);
            unsigned long long mask = __ballot(push);
            if (mask) {
                if (push) {
                    const float mx = -0.5f*PL.x, my = -0.5f*PL.y, mz = -0.5f*PL.z;
                    float inner = qx*mx; inner += qy*my; inner += qz*mz;
                    const float d = (sqn - 2.0f*inner) + PL.w;
                    unsigned uu = __float_as_uint(d);
                    unsigned e = uu ^ (((unsigned)((int)uu >> 31)) | 0x80000000u);
                    unsigned long long key = ((unsigned long long)e << 32) | (unsigned)si[sI];
                    int ofs = (int)__popcll(mask & ((1ull << lane) - 1ull));
                    ovf[cnt + ofs] = key;
                }
                cnt += (int)__popcll(mask);
            }
            lo = stL;
            dl = (lo == 0);
            PL = PLn; xL = xLn;
        }
        if (goR) {
            const int sI = hi + lane;
            const int sa = sI < NN-1 ? sI : NN-1;
            const bool valid = sI < enR;
            const float sc = fmaf(PR.x, qx, fmaf(PR.y, qy, fmaf(PR.z, qz, PR.w)));
            bool push = valid && (sc <= thr);
            unsigned long long mask = __ballot(push);
            if (mask) {
                if (push) {
                    const float mx = -0.5f*PR.x, my = -0.5f*PR.y, mz = -0.5f*PR.z;
                    float inner = qx*mx; inner += qy*my; inner += qz*mz;
                    const float d = (sqn - 2.0f*inner) + PR.w;
                    unsigned uu = __float_as_uint(d);
                    unsigned e = uu ^ (((unsigned)((int)uu >> 31)) | 0x80000000u);
                    unsigned long long key = ((unsigned long long)e << 32) | (unsigned)si[sa];
                    int ofs = (int)__popcll(mask & ((1ull << lane) - 1ull));
                    ovf[cnt + ofs] = key;
                }
                cnt += (int)__popcll(mask);
            }
            hi = enR;
            dr = (hi == NN);
            PR = PRn; xR = xRn;
        }
    }
    rank_flush(ovf, inc, scr, cnt, kthd, lane);

    /* coalesced write at sorted rank; main reads via rankArr */
    if (lane < KNN)
        idx_out[(size_t)s * KNN + lane] = (int)(unsigned)(inc[lane] & 0xFFFFFFFFull);

    /* moments epilogue: lanes 0..19 gather the 20 neighbors, 9 reductions */
    float nx = 0.f, ny = 0.f, nz = 0.f, xx = 0.f, xy = 0.f, xz = 0.f,
          yy = 0.f, yz = 0.f, zz = 0.f;
    if (lane < KNN) {
        int nbr = (int)(unsigned)(inc[lane] & 0xFFFFFFFFull);
        float4 pn = pts4[(b << 12) + nbr];
        nx = -0.5f*pn.x; ny = -0.5f*pn.y; nz = -0.5f*pn.z;
        xx = nx*nx; xy = nx*ny; xz = nx*nz; yy = ny*ny; yz = ny*nz; zz = nz*nz;
    }
#pragma unroll
    for (int off = 32; off > 0; off >>= 1) {
        nx += __shfl_xor(nx, off); ny += __shfl_xor(ny, off); nz += __shfl_xor(nz, off);
        xx += __shfl_xor(xx, off); xy += __shfl_xor(xy, off); xz += __shfl_xor(xz, off);
        yy += __shfl_xor(yy, off); yz += __shfl_xor(yz, off); zz += __shfl_xor(zz, off);
    }
    if (lane == 0) {
        MOM[wv][0] = nx;  MOM[wv][1] = ny;  MOM[wv][2] = nz;
        MOM[wv][3] = qx;  MOM[wv][4] = qy;  MOM[wv][5] = qz;
        MOM[wv][6] = xx;  MOM[wv][7] = xy;  MOM[wv][8] = xz;
        MOM[wv][9] = yy;  MOM[wv][10] = yz; MOM[wv][11] = zz;
        MOM[wv][12] = nx*qx; MOM[wv][13] = nx*qy; MOM[wv][14] = nx*qz;
        MOM[wv][15] = ny*qx; MOM[wv][16] = ny*qy; MOM[wv][17] = ny*qz;
        MOM[wv][18] = nz*qx; MOM[wv][19] = nz*qy; MOM[wv][20] = nz*qz;
        MOM[wv][21] = qx*qx; MOM[wv][22] = qx*qy; MOM[wv][23] = qx*qz;
        MOM[wv][24] = qy*qy; MOM[wv][25] = qy*qz; MOM[wv][26] = qz*qz;
    }
    __syncthreads();
    if (tid < 27)
        atomicAdd(&mstats[(blockIdx.x & (MCOPY-1))*27 + tid],
                  (double)(MOM[0][tid] + MOM[1][tid] + MOM[2][tid] + MOM[3][tid]));
}

/* split fp32 -> bf16 hi (truncate) + bf16 lo (truncated remainder) */
__device__ __forceinline__ void bsplit(float g, short& hi, short& lo) {
    unsigned bits = __float_as_uint(g);
    unsigned hbits = bits & 0xFFFF0000u;
    float rem = g - __uint_as_float(hbits);
    hi = (short)(bits >> 16);
    lo = (short)(__float_as_uint(rem) >> 16);
}

/* ---------------- K5: main pass — shared-leftover-tile split-bf16 MFMA --------- */
__global__ __launch_bounds__(256) void main_kernel(const int* __restrict__ idxb,
        const int* __restrict__ rankArr, const float4* __restrict__ pts4,
        const double* __restrict__ ms, const float* __restrict__ W1,
        const float* __restrict__ gamma1, const float* __restrict__ beta1,
        const float* __restrict__ W2,
        float* __restrict__ maxbuf, float* __restrict__ stats2f) {
    __shared__ __align__(16) short Thi[4][32*72];
    __shared__ __align__(16) short Tlo[4][32*72];
    __shared__ float chs[128];
    __shared__ float ab1s[128];
    __shared__ double msd[27];
    const int tid = threadIdx.x;
    const int lane = tid & 63;
    const int wv = __builtin_amdgcn_readfirstlane(tid >> 6);
    const int l15 = lane & 15;
    const int quad = lane >> 4;
    if (tid < 128) chs[tid] = 0.f;
    if (tid < 27) {                                /* sum the 32 mstats copies */
        double t = 0.0;
        for (int c = 0; c < MCOPY; ++c) t += ms[c*27 + tid];
        msd[tid] = t;
    }
    __syncthreads();
    if (tid < 64) {                                /* inline fin1m (bn1 affine) */
        int c = tid;
        double wu[3], wvv[3];
#pragma unroll
        for (int i = 0; i < 3; ++i) {
            wu[i] = (double)W1[c*6 + i];
            wvv[i] = (double)W1[c*6 + 3 + i] - wu[i];
        }
        const double S = (double)SAMPLES;
        double mean = (wu[0]*msd[0] + wu[1]*msd[1] + wu[2]*msd[2]
                     + 20.0*(wvv[0]*msd[3] + wvv[1]*msd[4] + wvv[2]*msd[5])) / S;
        double qM1 = wu[0]*wu[0]*msd[6] + wu[1]*wu[1]*msd[9] + wu[2]*wu[2]*msd[11]
                   + 2.0*(wu[0]*wu[1]*msd[7] + wu[0]*wu[2]*msd[8] + wu[1]*wu[2]*msd[10]);
        double cross = 0.0;
#pragma unroll
        for (int i = 0; i < 3; ++i)
#pragma unroll
            for (int j = 0; j < 3; ++j)
                cross += wu[i] * msd[12 + i*3 + j] * wvv[j];
        double qpp = wvv[0]*wvv[0]*msd[21] + wvv[1]*wvv[1]*msd[24] + wvv[2]*wvv[2]*msd[26]
                   + 2.0*(wvv[0]*wvv[1]*msd[22] + wvv[0]*wvv[2]*msd[23] + wvv[1]*wvv[2]*msd[25]);
        double e2 = (qM1 + 2.0*cross + 20.0*qpp) / S;
        double var = e2 - mean*mean;
        float a = (float)((double)gamma1[c] / sqrt(var + (double)EPSF));
        ab1s[c] = a;
        ab1s[64 + c] = beta1[c] - a * (float)mean;
    }
    __syncthreads();

    bf16x8 whi[8], wlo[8];
#pragma unroll
    for (int t = 0; t < 4; ++t)
#pragma unroll
    for (int f = 0; f < 2; ++f) {
        const int o = 16*t + l15;
        const int c0 = 32*f + quad*8;
        const float4* wr = (const float4*)(W2 + o*64 + c0);
        float4 w0 = wr[0], w1 = wr[1];
        float vals[8] = {w0.x,w0.y,w0.z,w0.w,w1.x,w1.y,w1.z,w1.w};
        bf16x8 h, l;
#pragma unroll
        for (int j = 0; j < 8; ++j) { short hj, lj; bsplit(vals[j], hj, lj); h[j]=hj; l[j]=lj; }
        whi[t*2+f] = h; wlo[t*2+f] = l;
    }

    const float w10 = W1[lane*6+0], w11 = W1[lane*6+1], w12 = W1[lane*6+2];
    const float w13 = W1[lane*6+3], w14 = W1[lane*6+4], w15 = W1[lane*6+5];
    const float a1 = ab1s[lane], b1 = ab1s[64 + lane];
    float ssum[4] = {0.f,0.f,0.f,0.f}, ssq[4] = {0.f,0.f,0.f,0.f};
    float lm[4][4];                                /* deferred tile1 max [point][t] */
    short* thi = &Thi[wv][0];
    short* tlo = &Tlo[wv][0];

    const int pt0 = (blockIdx.x * 4 + wv) * 4;
    const int b = pt0 >> 12;
    const float4* pb = pts4 + ((size_t)b << 12);
    const int* rnk = rankArr + ((size_t)b << 12);

    for (int p = 0; p < 4; ++p) {
        const int pt = pt0 + p;
        const float4 pc = pb[pt & (NN - 1)];
        const float X = -0.5f*pc.x, Y = -0.5f*pc.y, Z = -0.5f*pc.z;
        const float vc = (w13 - w10)*X + (w14 - w11)*Y + (w15 - w12)*Z;
        const int srow = rnk[pt & (NN - 1)];       /* uniform scalar lookup */
        const int* irow = idxb + ((size_t)((b << 12) + srow)) * KNN;
#pragma unroll
        for (int k = 0; k < KNN; ++k) {
            float4 pn = pb[irow[k]];
            float nx = -0.5f*pn.x, ny = -0.5f*pn.y, nz = -0.5f*pn.z;
            float uc = w10*nx + w11*ny + w12*nz;
            float g = a1 * (uc + vc) + b1;
            g = fmaxf(g, SLOPE * g);
            short hj, lj; bsplit(g, hj, lj);
            const int row = (k < 16) ? k : (16 + p*4 + (k - 16));
            thi[row*72 + lane] = hj;
            tlo[row*72 + lane] = lj;
        }
        __builtin_amdgcn_wave_barrier();

        bf16x8 ah1[2], al1[2];
#pragma unroll
        for (int f = 0; f < 2; ++f) {
            const int co = 32*f + quad*8;
            ah1[f] = *(const bf16x8*)&thi[l15*72 + co];
            al1[f] = *(const bf16x8*)&tlo[l15*72 + co];
        }

        f32x4 acc1[4];
#pragma unroll
        for (int t = 0; t < 4; ++t) acc1[t] = (f32x4)0.f;
#pragma unroll
        for (int t = 0; t < 4; ++t) {
#pragma unroll
            for (int f = 0; f < 2; ++f) {
                acc1[t] = __builtin_amdgcn_mfma_f32_16x16x32_bf16(ah1[f], whi[t*2+f], acc1[t], 0,0,0);
                acc1[t] = __builtin_amdgcn_mfma_f32_16x16x32_bf16(al1[f], whi[t*2+f], acc1[t], 0,0,0);
                acc1[t] = __builtin_amdgcn_mfma_f32_16x16x32_bf16(ah1[f], wlo[t*2+f], acc1[t], 0,0,0);
            }
        }
        __builtin_amdgcn_wave_barrier();           /* tile1 reads done before next p */

        /* tile1 epilogue: reduce over rows k=0..15 (quads), defer the write */
#pragma unroll
        for (int t = 0; t < 4; ++t) {
            float m1 = fmaxf(fmaxf(acc1[t][0], acc1[t][1]), fmaxf(acc1[t][2], acc1[t][3]));
            float s1 = acc1[t][0] + acc1[t][1] + acc1[t][2] + acc1[t][3];
            float q1 = acc1[t][0]*acc1[t][0] + acc1[t][1]*acc1[t][1]
                     + acc1[t][2]*acc1[t][2] + acc1[t][3]*acc1[t][3];
            m1 = fmaxf(m1, __shfl_xor(m1, 16)); m1 = fmaxf(m1, __shfl_xor(m1, 32));
            s1 += __shfl_xor(s1, 16); s1 += __shfl_xor(s1, 32);
            q1 += __shfl_xor(q1, 16); q1 += __shfl_xor(q1, 32);
            lm[p][t] = m1;
            ssum[t] += s1; ssq[t] += q1;
        }
    }

    /* combined leftover tile: rows = p*4+(k-16), read once, 24 MFMA */
    {
        bf16x8 ah2[2], al2[2];
#pragma unroll
        for (int f = 0; f < 2; ++f) {
            const int co = 32*f + quad*8;
            ah2[f] = *(const bf16x8*)&thi[(16 + l15)*72 + co];
            al2[f] = *(const bf16x8*)&tlo[(16 + l15)*72 + co];
        }
        f32x4 accC[4];
#pragma unroll
        for (int t = 0; t < 4; ++t) accC[t] = (f32x4)0.f;
#pragma unroll
        for (int t = 0; t < 4; ++t) {
#pragma unroll
            for (int f = 0; f < 2; ++f) {
                accC[t] = __builtin_amdgcn_mfma_f32_16x16x32_bf16(ah2[f], whi[t*2+f], accC[t], 0,0,0);
                accC[t] = __builtin_amdgcn_mfma_f32_16x16x32_bf16(al2[f], whi[t*2+f], accC[t], 0,0,0);
                accC[t] = __builtin_amdgcn_mfma_f32_16x16x32_bf16(ah2[f], wlo[t*2+f], accC[t], 0,0,0);
            }
        }
        /* C row = quad*4+reg -> point = quad, k = 16+reg. */
#pragma unroll
        for (int t = 0; t < 4; ++t) {
            float cm = fmaxf(fmaxf(accC[t][0], accC[t][1]), fmaxf(accC[t][2], accC[t][3]));
            float cs = accC[t][0] + accC[t][1] + accC[t][2] + accC[t][3];
            float cq = accC[t][0]*accC[t][0] + accC[t][1]*accC[t][1]
                     + accC[t][2]*accC[t][2] + accC[t][3]*accC[t][3];
            float lmq = (quad == 0) ? lm[0][t] : (quad == 1) ? lm[1][t]
                      : (quad == 2) ? lm[2][t] : lm[3][t];
            maxbuf[((size_t)(pt0 + quad) << 6) + 16*t + l15] = fmaxf(lmq, cm);
            cs += __shfl_xor(cs, 16); cs += __shfl_xor(cs, 32);
            cq += __shfl_xor(cq, 16); cq += __shfl_xor(cq, 32);
            ssum[t] += cs; ssq[t] += cq;
        }
    }

    if (quad == 0) {
#pragma unroll
        for (int t = 0; t < 4; ++t) {
            atomicAdd(&chs[16*t + l15], ssum[t]);
            atomicAdd(&chs[64 + 16*t + l15], ssq[t]);
        }
    }
    __syncthreads();
    if (tid < 128)
        atomicAdd(&stats2f[(blockIdx.x & 1)*128 + tid], chs[tid]);
}

/* ---------------- K7: epilogue — fin2 inlined; transpose + bn2 + lrelu --------- */
__global__ __launch_bounds__(256) void out_kernel(const float* __restrict__ maxbuf,
        const float* __restrict__ s2f, const float* __restrict__ gamma2,
        const float* __restrict__ beta2, float* __restrict__ out) {
    __shared__ float t[64][65];
    __shared__ float ab2s[128];
    const int tid = threadIdx.x;
    if (tid < 64) {                                /* inline fin2 */
        int o = tid;
        double sum = (double)s2f[o] + (double)s2f[128 + o];
        double sq  = (double)s2f[64 + o] + (double)s2f[192 + o];
        double cnt = (double)SAMPLES;
        double mean = sum / cnt;
        double var  = sq / cnt - mean*mean;
        float a = (float)((double)gamma2[o] / sqrt(var + (double)EPSF));
        ab2s[o] = a;
        ab2s[64 + o] = beta2[o] - a * (float)mean;
    }
    const int b = blockIdx.x >> 6;
    const int n0 = (blockIdx.x & 63) << 6;
#pragma unroll
    for (int i = 0; i < 16; ++i) {
        int r = (tid >> 6) + i*4;
        int c = tid & 63;
        t[r][c] = maxbuf[(((size_t)((b << 12) + n0 + r)) << 6) + c];
    }
    __syncthreads();
#pragma unroll
    for (int i = 0; i < 16; ++i) {
        int o = (tid >> 6) + i*4;
        int nn = tid & 63;
        float a = ab2s[o], bb = ab2s[64 + o];
        float h = a * t[nn][o] + bb;
        out[(((size_t)(b*64 + o)) << 12) + n0 + nn] = h >= 0.f ? h : SLOPE*h;
    }
}

extern "C" void kernel_launch(void* const* d_in, const int* in_sizes, int n_in,
                              void* d_out, int out_size, void* d_ws, size_t ws_size,
                              hipStream_t stream) {
    const float* x      = (const float*)d_in[0];
    const float* W1     = (const float*)d_in[1];
    const float* gamma1 = (const float*)d_in[2];
    const float* beta1  = (const float*)d_in[3];
    const float* W2     = (const float*)d_in[4];
    const float* gamma2 = (const float*)d_in[5];
    const float* beta2  = (const float*)d_in[6];
    float* out = (float*)d_out;

    char* ws = (char*)d_ws;
    int*    idxb    = (int*)   (ws + 0);           /* 2,621,440 B (sorted order) */
    float4* pts4    = (float4*)(ws + 2621440);     /* 512 KB */
    float4* sp4     = (float4*)(ws + 3145728);     /* 512 KB sorted pts */
    int*    sidx    = (int*)   (ws + 3670016);     /* 128 KB sorted->orig */
    int*    rankArr = (int*)   (ws + 3801088);     /* 128 KB orig->sorted */
    float*  maxbuf  = (float*) (ws + 19398656);    /* 8,388,608 B, (b,n,o) */
    double* mstats  = (double*)(ws + 27787264);    /* 32x27 doubles = 6912 B */
    float*  stats2f = (float*) (ws + 27794176);    /* 2x128 floats = 1024 B */
    double* zreg    = (double*)(ws + 27787264);    /* zero region: 992 doubles */

    sort_kernel <<<8, 1024, 0, stream>>>(x, pts4, sp4, sidx, rankArr, zreg);
    knn_kernel  <<<8192, 256, 0, stream>>>(pts4, sp4, sidx, idxb, mstats);
    main_kernel <<<2048, 256, 0, stream>>>(idxb, rankArr, pts4, mstats, W1, gamma1,
                                           beta1, W2, maxbuf, stats2f);
    out_kernel  <<<512, 256, 0, stream>>>(maxbuf, stats2f, gamma2, beta2, out);
}

// Round 9
// 255.194 us; speedup vs baseline: 3.0482x; 1.0110x over previous
//
#include <hip/hip_runtime.h>
#include <hip/hip_bf16.h>
#include <math.h>

#define BB 8
#define NN 4096
#define KNN 20
#define CH 64
#define SAMPLES (BB*NN*KNN)   /* 655360 */
#define EPSF 1e-5f
#define SLOPE 0.2f
#define MCOPY 32              /* mstats copies to spread atomic contention */

typedef float f32x4 __attribute__((ext_vector_type(4)));
typedef short bf16x8 __attribute__((ext_vector_type(8)));

/* decode order-preserving uint back to float */
__device__ __forceinline__ float key_decode(unsigned e) {
    return __uint_as_float((e & 0x80000000u) ? (e ^ 0x80000000u) : ~e);
}

/* rank-select flush: merge ovf[0..cnt) + inc[0..19] -> new exact top-20 in inc. */
__device__ __forceinline__ void rank_flush(unsigned long long* ovf,
                                           unsigned long long* inc,
                                           unsigned long long* scr,
                                           int& cnt, float& kthd, int lane) {
    while (cnt > 0) {
        int take = cnt < 44 ? cnt : 44;
        unsigned long long key;
        if (lane < take)      key = ovf[cnt - take + lane];
        else if (lane >= 44)  key = inc[lane - 44];
        else                  key = ~0ull;
        scr[lane] = key;
        __builtin_amdgcn_wave_barrier();
        int r = 0;
#pragma unroll
        for (int t = 0; t < 64; ++t) {
            unsigned long long kt = scr[t];       /* uniform addr -> broadcast */
            r += (kt < key) ? 1 : 0;
        }
        __builtin_amdgcn_wave_barrier();
        if (r < KNN) inc[r] = key;                /* padding ranks land >= 20 */
        __builtin_amdgcn_wave_barrier();
        kthd = key_decode((unsigned)(inc[KNN-1] >> 32));
        cnt -= take;
    }
}

/* ---------------- K0: per-batch: build pts4 + bitonic sort by x + zero stats --- */
__global__ __launch_bounds__(1024) void sort_kernel(const float* __restrict__ x,
        float4* __restrict__ pts4, float4* __restrict__ sp4, int* __restrict__ sidx,
        int* __restrict__ rankArr, double* __restrict__ zreg) {
#pragma clang fp contract(off)
    __shared__ unsigned long long S[NN];                     /* 32 KB */
    const int tid = threadIdx.x;
    const int b = blockIdx.x;
    if (b == 0 && tid < 992) zreg[tid] = 0.0;     /* mstats(864d) + stats2f(128d) */
    const float* xb = x + (size_t)b * 3 * NN;
    for (int i = tid; i < NN; i += 1024) {
        float mx = xb[i], my = xb[NN + i], mz = xb[2*NN + i];
        float sq = mx*mx; sq += my*my; sq += mz*mz;          /* ref summation order */
        pts4[(b << 12) + i] = make_float4(-2.0f*mx, -2.0f*my, -2.0f*mz, sq);
        unsigned uu = __float_as_uint(mx);
        unsigned e = uu ^ (((unsigned)((int)uu >> 31)) | 0x80000000u);
        S[i] = ((unsigned long long)e << 32) | (unsigned)i;
    }
    __syncthreads();
    for (int k = 2; k <= NN; k <<= 1) {
        for (int j = k >> 1; j > 0; j >>= 1) {
#pragma unroll
            for (int tt = 0; tt < 2; ++tt) {
                int t = tid + tt*1024;            /* 2048 pairs */
                int i = ((t & ~(j - 1)) << 1) | (t & (j - 1));
                int h = i | j;
                unsigned long long a = S[i], c = S[h];
                bool up = ((i & k) == 0);
                if ((a > c) == up) { S[i] = c; S[h] = a; }
            }
            __syncthreads();
        }
    }
    for (int s = tid; s < NN; s += 1024) {
        int oi = (int)(unsigned)(S[s] & 0xFFFFFFFFu);
        float mx = xb[oi], my = xb[NN + oi], mz = xb[2*NN + oi];  /* recompute: no RAW */
        float sq = mx*mx; sq += my*my; sq += mz*mz;
        sp4[(b << 12) + s] = make_float4(-2.0f*mx, -2.0f*my, -2.0f*mz, sq);
        sidx[(b << 12) + s] = oi;
        rankArr[(b << 12) + oi] = s;
    }
}

/* ---------------- K1: exact KNN — pipelined sorted sweep, 128-wide side steps.
   Each live side advances 128 ranks/iteration (two 64-groups held in prefetch
   registers), halving per-iteration fixed costs vs the 64-wide sweep.  Prune
   test unchanged (boundary-x of the whole block: conservative — only ever
   scans MORE).  Filter keys, margin M, exact-d, rank-select flush identical
   to the verified kernel.  idx_out at sorted rank. ---------------------------- */
__global__ __launch_bounds__(256) void knn_kernel(const float4* __restrict__ pts4,
        const float4* __restrict__ sp4, const int* __restrict__ sidx,
        int* __restrict__ idx_out, double* __restrict__ mstats) {
#pragma clang fp contract(off)
    __shared__ unsigned long long OVF[4][296];               /* 9.25 KB */
    __shared__ unsigned long long INC[4][24];
    __shared__ unsigned long long SCR[4][64];
    __shared__ float MOM[4][27];
    const int tid = threadIdx.x;
    const int lane = tid & 63;
    const int wv = __builtin_amdgcn_readfirstlane(tid >> 6);
    const int s = blockIdx.x * 4 + wv;                       /* sorted-rank query */
    const int b = s >> 12;
    const int ss = s & (NN - 1);
    const float4* sb = sp4 + ((size_t)b << 12);
    const int* si = sidx + ((size_t)b << 12);
    unsigned long long* ovf = &OVF[wv][0];
    unsigned long long* inc = &INC[wv][0];
    unsigned long long* scr = &SCR[wv][0];

    const float4 Qc = sb[ss];
    const float qx = -0.5f*Qc.x, qy = -0.5f*Qc.y, qz = -0.5f*Qc.z; /* exact coords */
    const float sqn = Qc.w;
    int c0 = ss - 32; c0 = c0 < 0 ? 0 : (c0 > NN-64 ? NN-64 : c0);
    float kthd, thr, M;
    int cnt = 0;

    /* prefill: exact d for the 64 nearest-in-x, rank-select directly */
    {
        const float4 P = sb[c0 + lane];
        const float mx = -0.5f*P.x, my = -0.5f*P.y, mz = -0.5f*P.z;
        float inner = qx*mx; inner += qy*my; inner += qz*mz;
        const float d = (sqn - 2.0f*inner) + P.w;            /* ref parenthesization */
        unsigned uu = __float_as_uint(d);
        unsigned e = uu ^ (((unsigned)((int)uu >> 31)) | 0x80000000u);
        unsigned long long key = ((unsigned long long)e << 32) | (unsigned)si[c0 + lane];
        scr[lane] = key;
        __builtin_amdgcn_wave_barrier();
        int r = 0;
#pragma unroll
        for (int t = 0; t < 64; ++t) {
            unsigned long long kt = scr[t];
            r += (kt < key) ? 1 : 0;
        }
        __builtin_amdgcn_wave_barrier();
        if (r < KNN) inc[r] = key;
        __builtin_amdgcn_wave_barrier();
        kthd = key_decode((unsigned)(inc[KNN-1] >> 32));
        M = 1e-3f*(fabsf(kthd) + fabsf(sqn) + 1.0f);
        thr = (kthd - sqn) + M;
    }

    int lo = c0, hi = c0 + 64;
    bool dl = (lo == 0), dr = (hi == NN);

    /* prime the pipeline: 128-wide block + boundary x for each live side.
       Left addresses never exceed max(lo-65, 127) < NN: no clamp needed. */
    float4 PL0, PL1, PR0, PR1;
    float xL = 0.f, xR = 0.f;
    if (!dl) {
        int base = lo - 128; base = base < 0 ? 0 : base;
        PL0 = sb[base + lane];
        PL1 = sb[base + 64 + lane];
        xL = sb[lo - 1].x;
    }
    if (!dr) {
        int s0 = hi + lane;      int a0 = s0 < NN-1 ? s0 : NN-1;
        int s1 = hi + 64 + lane; int a1 = s1 < NN-1 ? s1 : NN-1;
        PR0 = sb[a0]; PR1 = sb[a1];
        xR = sb[hi].x;
    }

    while (!dl || !dr) {
        bool goL = false, goR = false;
        if (!dl) {                                 /* checks on PREFETCHED x: no stall */
            const float dx = qx - (-0.5f*xL);
            goL = (dx*dx <= kthd + M);
            if (!goL) dl = true;
        }
        if (!dr) {
            const float dx = (-0.5f*xR) - qx;
            goR = (dx*dx <= kthd + M);
            if (!goR) dr = true;
        }
        const int baseL = (lo - 128) < 0 ? 0 : (lo - 128);
        const int enR   = (hi + 128) > NN ? NN : (hi + 128);

        /* issue next-iteration prefetches before doing any work */
        float4 PL0n = PL0, PL1n = PL1, PR0n = PR0, PR1n = PR1;
        float xLn = 0.f, xRn = 0.f;
        if (goL && baseL > 0) {
            int b2 = baseL - 128; b2 = b2 < 0 ? 0 : b2;
            PL0n = sb[b2 + lane];
            PL1n = sb[b2 + 64 + lane];
            xLn = sb[baseL - 1].x;
        }
        if (goR && enR < NN) {
            int s0 = enR + lane;      int a0 = s0 < NN-1 ? s0 : NN-1;
            int s1 = enR + 64 + lane; int a1 = s1 < NN-1 ? s1 : NN-1;
            PR0n = sb[a0]; PR1n = sb[a1];
            xRn = sb[enR].x;
        }

        if (cnt > 32) {                            /* LDS flush overlaps the loads */
            rank_flush(ovf, inc, scr, cnt, kthd, lane);
            M = 1e-3f*(fabsf(kthd) + fabsf(sqn) + 1.0f);
            thr = (kthd - sqn) + M;
        }

        if (goL) {
#pragma unroll
            for (int j = 0; j < 2; ++j) {
                const float4 P = (j == 0) ? PL0 : PL1;
                const int sI = baseL + j*64 + lane;
                const bool valid = sI < lo;
                const float sc = fmaf(P.x, qx, fmaf(P.y, qy, fmaf(P.z, qz, P.w)));
                bool push = valid && (sc <= thr);
                unsigned long long mask = __ballot(push);
                if (mask) {
                    if (push) {
                        const float mx = -0.5f*P.x, my = -0.5f*P.y, mz = -0.5f*P.z;
                        float inner = qx*mx; inner += qy*my; inner += qz*mz;
                        const float d = (sqn - 2.0f*inner) + P.w;
                        unsigned uu = __float_as_uint(d);
                        unsigned e = uu ^ (((unsigned)((int)uu >> 31)) | 0x80000000u);
                        unsigned long long key = ((unsigned long long)e << 32) | (unsigned)si[sI];
                        int ofs = (int)__popcll(mask & ((1ull << lane) - 1ull));
                        ovf[cnt + ofs] = key;
                    }
                    cnt += (int)__popcll(mask);
                }
            }
            lo = baseL;
            dl = (lo == 0);
            PL0 = PL0n; PL1 = PL1n; xL = xLn;
        }
        if (goR) {
#pragma unroll
            for (int j = 0; j < 2; ++j) {
                const float4 P = (j == 0) ? PR0 : PR1;
                const int sI = hi + j*64 + lane;
                const bool valid = sI < enR;
                const float sc = fmaf(P.x, qx, fmaf(P.y, qy, fmaf(P.z, qz, P.w)));
                bool push = valid && (sc <= thr);
                unsigned long long mask = __ballot(push);
                if (mask) {
                    if (push) {
                        const float mx = -0.5f*P.x, my = -0.5f*P.y, mz = -0.5f*P.z;
                        float inner = qx*mx; inner += qy*my; inner += qz*mz;
                        const float d = (sqn - 2.0f*inner) + P.w;
                        unsigned uu = __float_as_uint(d);
                        unsigned e = uu ^ (((unsigned)((int)uu >> 31)) | 0x80000000u);
                        unsigned long long key = ((unsigned long long)e << 32) | (unsigned)si[sI];
                        int ofs = (int)__popcll(mask & ((1ull << lane) - 1ull));
                        ovf[cnt + ofs] = key;
                    }
                    cnt += (int)__popcll(mask);
                }
            }
            hi = enR;
            dr = (hi == NN);
            PR0 = PR0n; PR1 = PR1n; xR = xRn;
        }
    }
    rank_flush(ovf, inc, scr, cnt, kthd, lane);

    /* coalesced write at sorted rank; main reads via rankArr */
    if (lane < KNN)
        idx_out[(size_t)s * KNN + lane] = (int)(unsigned)(inc[lane] & 0xFFFFFFFFull);

    /* moments epilogue: lanes 0..19 gather the 20 neighbors, 9 reductions
       (lanes >= 32 hold zeros: off=32 step elided) */
    float nx = 0.f, ny = 0.f, nz = 0.f, xx = 0.f, xy = 0.f, xz = 0.f,
          yy = 0.f, yz = 0.f, zz = 0.f;
    if (lane < KNN) {
        int nbr = (int)(unsigned)(inc[lane] & 0xFFFFFFFFull);
        float4 pn = pts4[(b << 12) + nbr];
        nx = -0.5f*pn.x; ny = -0.5f*pn.y; nz = -0.5f*pn.z;
        xx = nx*nx; xy = nx*ny; xz = nx*nz; yy = ny*ny; yz = ny*nz; zz = nz*nz;
    }
#pragma unroll
    for (int off = 16; off > 0; off >>= 1) {
        nx += __shfl_xor(nx, off); ny += __shfl_xor(ny, off); nz += __shfl_xor(nz, off);
        xx += __shfl_xor(xx, off); xy += __shfl_xor(xy, off); xz += __shfl_xor(xz, off);
        yy += __shfl_xor(yy, off); yz += __shfl_xor(yz, off); zz += __shfl_xor(zz, off);
    }
    if (lane == 0) {
        MOM[wv][0] = nx;  MOM[wv][1] = ny;  MOM[wv][2] = nz;
        MOM[wv][3] = qx;  MOM[wv][4] = qy;  MOM[wv][5] = qz;
        MOM[wv][6] = xx;  MOM[wv][7] = xy;  MOM[wv][8] = xz;
        MOM[wv][9] = yy;  MOM[wv][10] = yz; MOM[wv][11] = zz;
        MOM[wv][12] = nx*qx; MOM[wv][13] = nx*qy; MOM[wv][14] = nx*qz;
        MOM[wv][15] = ny*qx; MOM[wv][16] = ny*qy; MOM[wv][17] = ny*qz;
        MOM[wv][18] = nz*qx; MOM[wv][19] = nz*qy; MOM[wv][20] = nz*qz;
        MOM[wv][21] = qx*qx; MOM[wv][22] = qx*qy; MOM[wv][23] = qx*qz;
        MOM[wv][24] = qy*qy; MOM[wv][25] = qy*qz; MOM[wv][26] = qz*qz;
    }
    __syncthreads();
    if (tid < 27)
        atomicAdd(&mstats[(blockIdx.x & (MCOPY-1))*27 + tid],
                  (double)(MOM[0][tid] + MOM[1][tid] + MOM[2][tid] + MOM[3][tid]));
}

/* split fp32 -> bf16 hi (truncate) + bf16 lo (truncated remainder) */
__device__ __forceinline__ void bsplit(float g, short& hi, short& lo) {
    unsigned bits = __float_as_uint(g);
    unsigned hbits = bits & 0xFFFF0000u;
    float rem = g - __uint_as_float(hbits);
    hi = (short)(bits >> 16);
    lo = (short)(__float_as_uint(rem) >> 16);
}

/* ---------------- K5: main pass — shared-leftover-tile split-bf16 MFMA --------- */
__global__ __launch_bounds__(256) void main_kernel(const int* __restrict__ idxb,
        const int* __restrict__ rankArr, const float4* __restrict__ pts4,
        const double* __restrict__ ms, const float* __restrict__ W1,
        const float* __restrict__ gamma1, const float* __restrict__ beta1,
        const float* __restrict__ W2,
        float* __restrict__ maxbuf, float* __restrict__ stats2f) {
    __shared__ __align__(16) short Thi[4][32*72];
    __shared__ __align__(16) short Tlo[4][32*72];
    __shared__ float chs[128];
    __shared__ float ab1s[128];
    __shared__ double msd[27];
    const int tid = threadIdx.x;
    const int lane = tid & 63;
    const int wv = __builtin_amdgcn_readfirstlane(tid >> 6);
    const int l15 = lane & 15;
    const int quad = lane >> 4;
    if (tid < 128) chs[tid] = 0.f;
    if (tid < 27) {                                /* sum the 32 mstats copies */
        double t = 0.0;
        for (int c = 0; c < MCOPY; ++c) t += ms[c*27 + tid];
        msd[tid] = t;
    }
    __syncthreads();
    if (tid < 64) {                                /* inline fin1m (bn1 affine) */
        int c = tid;
        double wu[3], wvv[3];
#pragma unroll
        for (int i = 0; i < 3; ++i) {
            wu[i] = (double)W1[c*6 + i];
            wvv[i] = (double)W1[c*6 + 3 + i] - wu[i];
        }
        const double S = (double)SAMPLES;
        double mean = (wu[0]*msd[0] + wu[1]*msd[1] + wu[2]*msd[2]
                     + 20.0*(wvv[0]*msd[3] + wvv[1]*msd[4] + wvv[2]*msd[5])) / S;
        double qM1 = wu[0]*wu[0]*msd[6] + wu[1]*wu[1]*msd[9] + wu[2]*wu[2]*msd[11]
                   + 2.0*(wu[0]*wu[1]*msd[7] + wu[0]*wu[2]*msd[8] + wu[1]*wu[2]*msd[10]);
        double cross = 0.0;
#pragma unroll
        for (int i = 0; i < 3; ++i)
#pragma unroll
            for (int j = 0; j < 3; ++j)
                cross += wu[i] * msd[12 + i*3 + j] * wvv[j];
        double qpp = wvv[0]*wvv[0]*msd[21] + wvv[1]*wvv[1]*msd[24] + wvv[2]*wvv[2]*msd[26]
                   + 2.0*(wvv[0]*wvv[1]*msd[22] + wvv[0]*wvv[2]*msd[23] + wvv[1]*wvv[2]*msd[25]);
        double e2 = (qM1 + 2.0*cross + 20.0*qpp) / S;
        double var = e2 - mean*mean;
        float a = (float)((double)gamma1[c] / sqrt(var + (double)EPSF));
        ab1s[c] = a;
        ab1s[64 + c] = beta1[c] - a * (float)mean;
    }
    __syncthreads();

    bf16x8 whi[8], wlo[8];
#pragma unroll
    for (int t = 0; t < 4; ++t)
#pragma unroll
    for (int f = 0; f < 2; ++f) {
        const int o = 16*t + l15;
        const int c0 = 32*f + quad*8;
        const float4* wr = (const float4*)(W2 + o*64 + c0);
        float4 w0 = wr[0], w1 = wr[1];
        float vals[8] = {w0.x,w0.y,w0.z,w0.w,w1.x,w1.y,w1.z,w1.w};
        bf16x8 h, l;
#pragma unroll
        for (int j = 0; j < 8; ++j) { short hj, lj; bsplit(vals[j], hj, lj); h[j]=hj; l[j]=lj; }
        whi[t*2+f] = h; wlo[t*2+f] = l;
    }

    const float w10 = W1[lane*6+0], w11 = W1[lane*6+1], w12 = W1[lane*6+2];
    const float w13 = W1[lane*6+3], w14 = W1[lane*6+4], w15 = W1[lane*6+5];
    const float a1 = ab1s[lane], b1 = ab1s[64 + lane];
    float ssum[4] = {0.f,0.f,0.f,0.f}, ssq[4] = {0.f,0.f,0.f,0.f};
    float lm[4][4];                                /* deferred tile1 max [point][t] */
    short* thi = &Thi[wv][0];
    short* tlo = &Tlo[wv][0];

    const int pt0 = (blockIdx.x * 4 + wv) * 4;
    const int b = pt0 >> 12;
    const float4* pb = pts4 + ((size_t)b << 12);
    const int* rnk = rankArr + ((size_t)b << 12);

    for (int p = 0; p < 4; ++p) {
        const int pt = pt0 + p;
        const float4 pc = pb[pt & (NN - 1)];
        const float X = -0.5f*pc.x, Y = -0.5f*pc.y, Z = -0.5f*pc.z;
        const float vc = (w13 - w10)*X + (w14 - w11)*Y + (w15 - w12)*Z;
        const int srow = rnk[pt & (NN - 1)];       /* uniform scalar lookup */
        const int* irow = idxb + ((size_t)((b << 12) + srow)) * KNN;
#pragma unroll
        for (int k = 0; k < KNN; ++k) {
            float4 pn = pb[irow[k]];
            float nx = -0.5f*pn.x, ny = -0.5f*pn.y, nz = -0.5f*pn.z;
            float uc = w10*nx + w11*ny + w12*nz;
            float g = a1 * (uc + vc) + b1;
            g = fmaxf(g, SLOPE * g);
            short hj, lj; bsplit(g, hj, lj);
            const int row = (k < 16) ? k : (16 + p*4 + (k - 16));
            thi[row*72 + lane] = hj;
            tlo[row*72 + lane] = lj;
        }
        __builtin_amdgcn_wave_barrier();

        bf16x8 ah1[2], al1[2];
#pragma unroll
        for (int f = 0; f < 2; ++f) {
            const int co = 32*f + quad*8;
            ah1[f] = *(const bf16x8*)&thi[l15*72 + co];
            al1[f] = *(const bf16x8*)&tlo[l15*72 + co];
        }

        f32x4 acc1[4];
#pragma unroll
        for (int t = 0; t < 4; ++t) acc1[t] = (f32x4)0.f;
#pragma unroll
        for (int t = 0; t < 4; ++t) {
#pragma unroll
            for (int f = 0; f < 2; ++f) {
                acc1[t] = __builtin_amdgcn_mfma_f32_16x16x32_bf16(ah1[f], whi[t*2+f], acc1[t], 0,0,0);
                acc1[t] = __builtin_amdgcn_mfma_f32_16x16x32_bf16(al1[f], whi[t*2+f], acc1[t], 0,0,0);
                acc1[t] = __builtin_amdgcn_mfma_f32_16x16x32_bf16(ah1[f], wlo[t*2+f], acc1[t], 0,0,0);
            }
        }
        __builtin_amdgcn_wave_barrier();           /* tile1 reads done before next p */

        /* tile1 epilogue: reduce over rows k=0..15 (quads), defer the write */
#pragma unroll
        for (int t = 0; t < 4; ++t) {
            float m1 = fmaxf(fmaxf(acc1[t][0], acc1[t][1]), fmaxf(acc1[t][2], acc1[t][3]));
            float s1 = acc1[t][0] + acc1[t][1] + acc1[t][2] + acc1[t][3];
            float q1 = acc1[t][0]*acc1[t][0] + acc1[t][1]*acc1[t][1]
                     + acc1[t][2]*acc1[t][2] + acc1[t][3]*acc1[t][3];
            m1 = fmaxf(m1, __shfl_xor(m1, 16)); m1 = fmaxf(m1, __shfl_xor(m1, 32));
            s1 += __shfl_xor(s1, 16); s1 += __shfl_xor(s1, 32);
            q1 += __shfl_xor(q1, 16); q1 += __shfl_xor(q1, 32);
            lm[p][t] = m1;
            ssum[t] += s1; ssq[t] += q1;
        }
    }

    /* combined leftover tile: rows = p*4+(k-16), read once, 24 MFMA */
    {
        bf16x8 ah2[2], al2[2];
#pragma unroll
        for (int f = 0; f < 2; ++f) {
            const int co = 32*f + quad*8;
            ah2[f] = *(const bf16x8*)&thi[(16 + l15)*72 + co];
            al2[f] = *(const bf16x8*)&tlo[(16 + l15)*72 + co];
        }
        f32x4 accC[4];
#pragma unroll
        for (int t = 0; t < 4; ++t) accC[t] = (f32x4)0.f;
#pragma unroll
        for (int t = 0; t < 4; ++t) {
#pragma unroll
            for (int f = 0; f < 2; ++f) {
                accC[t] = __builtin_amdgcn_mfma_f32_16x16x32_bf16(ah2[f], whi[t*2+f], accC[t], 0,0,0);
                accC[t] = __builtin_amdgcn_mfma_f32_16x16x32_bf16(al2[f], whi[t*2+f], accC[t], 0,0,0);
                accC[t] = __builtin_amdgcn_mfma_f32_16x16x32_bf16(ah2[f], wlo[t*2+f], accC[t], 0,0,0);
            }
        }
        /* C row = quad*4+reg -> point = quad, k = 16+reg. */
#pragma unroll
        for (int t = 0; t < 4; ++t) {
            float cm = fmaxf(fmaxf(accC[t][0], accC[t][1]), fmaxf(accC[t][2], accC[t][3]));
            float cs = accC[t][0] + accC[t][1] + accC[t][2] + accC[t][3];
            float cq = accC[t][0]*accC[t][0] + accC[t][1]*accC[t][1]
                     + accC[t][2]*accC[t][2] + accC[t][3]*accC[t][3];
            float lmq = (quad == 0) ? lm[0][t] : (quad == 1) ? lm[1][t]
                      : (quad == 2) ? lm[2][t] : lm[3][t];
            maxbuf[((size_t)(pt0 + quad) << 6) + 16*t + l15] = fmaxf(lmq, cm);
            cs += __shfl_xor(cs, 16); cs += __shfl_xor(cs, 32);
            cq += __shfl_xor(cq, 16); cq += __shfl_xor(cq, 32);
            ssum[t] += cs; ssq[t] += cq;
        }
    }

    if (quad == 0) {
#pragma unroll
        for (int t = 0; t < 4; ++t) {
            atomicAdd(&chs[16*t + l15], ssum[t]);
            atomicAdd(&chs[64 + 16*t + l15], ssq[t]);
        }
    }
    __syncthreads();
    if (tid < 128)
        atomicAdd(&stats2f[(blockIdx.x & 1)*128 + tid], chs[tid]);
}

/* ---------------- K7: epilogue — fin2 inlined; transpose + bn2 + lrelu --------- */
__global__ __launch_bounds__(256) void out_kernel(const float* __restrict__ maxbuf,
        const float* __restrict__ s2f, const float* __restrict__ gamma2,
        const float* __restrict__ beta2, float* __restrict__ out) {
    __shared__ float t[64][65];
    __shared__ float ab2s[128];
    const int tid = threadIdx.x;
    if (tid < 64) {                                /* inline fin2 */
        int o = tid;
        double sum = (double)s2f[o] + (double)s2f[128 + o];
        double sq  = (double)s2f[64 + o] + (double)s2f[192 + o];
        double cnt = (double)SAMPLES;
        double mean = sum / cnt;
        double var  = sq / cnt - mean*mean;
        float a = (float)((double)gamma2[o] / sqrt(var + (double)EPSF));
        ab2s[o] = a;
        ab2s[64 + o] = beta2[o] - a * (float)mean;
    }
    const int b = blockIdx.x >> 6;
    const int n0 = (blockIdx.x & 63) << 6;
#pragma unroll
    for (int i = 0; i < 16; ++i) {
        int r = (tid >> 6) + i*4;
        int c = tid & 63;
        t[r][c] = maxbuf[(((size_t)((b << 12) + n0 + r)) << 6) + c];
    }
    __syncthreads();
#pragma unroll
    for (int i = 0; i < 16; ++i) {
        int o = (tid >> 6) + i*4;
        int nn = tid & 63;
        float a = ab2s[o], bb = ab2s[64 + o];
        float h = a * t[nn][o] + bb;
        out[(((size_t)(b*64 + o)) << 12) + n0 + nn] = h >= 0.f ? h : SLOPE*h;
    }
}

extern "C" void kernel_launch(void* const* d_in, const int* in_sizes, int n_in,
                              void* d_out, int out_size, void* d_ws, size_t ws_size,
                              hipStream_t stream) {
    const float* x      = (const float*)d_in[0];
    const float* W1     = (const float*)d_in[1];
    const float* gamma1 = (const float*)d_in[2];
    const float* beta1  = (const float*)d_in[3];
    const float* W2     = (const float*)d_in[4];
    const float* gamma2 = (const float*)d_in[5];
    const float* beta2  = (const float*)d_in[6];
    float* out = (float*)d_out;

    char* ws = (char*)d_ws;
    int*    idxb    = (int*)   (ws + 0);           /* 2,621,440 B (sorted order) */
    float4* pts4    = (float4*)(ws + 2621440);     /* 512 KB */
    float4* sp4     = (float4*)(ws + 3145728);     /* 512 KB sorted pts */
    int*    sidx    = (int*)   (ws + 3670016);     /* 128 KB sorted->orig */
    int*    rankArr = (int*)   (ws + 3801088);     /* 128 KB orig->sorted */
    float*  maxbuf  = (float*) (ws + 19398656);    /* 8,388,608 B, (b,n,o) */
    double* mstats  = (double*)(ws + 27787264);    /* 32x27 doubles = 6912 B */
    float*  stats2f = (float*) (ws + 27794176);    /* 2x128 floats = 1024 B */
    double* zreg    = (double*)(ws + 27787264);    /* zero region: 992 doubles */

    sort_kernel <<<8, 1024, 0, stream>>>(x, pts4, sp4, sidx, rankArr, zreg);
    knn_kernel  <<<8192, 256, 0, stream>>>(pts4, sp4, sidx, idxb, mstats);
    main_kernel <<<2048, 256, 0, stream>>>(idxb, rankArr, pts4, mstats, W1, gamma1,
                                           beta1, W2, maxbuf, stats2f);
    out_kernel  <<<512, 256, 0, stream>>>(maxbuf, stats2f, gamma2, beta2, out);
}